// Round 1
// baseline (471.692 us; speedup 1.0000x reference)
//
#include <hip/hip_runtime.h>
#include <hip/hip_bf16.h>

#define T_TOK 2048
#define HDIM 1024
#define IDIM 512
#define ISDIM 1024
#define NEXP 16
#define TOPK 4
#define NSLOT (T_TOK*TOPK)
#define SCALE_F 2.5f

typedef unsigned short u16;
typedef float f32x4 __attribute__((ext_vector_type(4)));
typedef __bf16 bf16x8 __attribute__((ext_vector_type(8)));
typedef u16 u16x8 __attribute__((ext_vector_type(8)));

__device__ __forceinline__ u16 f2bf(float f) {
  unsigned u = __builtin_bit_cast(unsigned, f);
  u += 0x7fffu + ((u >> 16) & 1u);   // round-to-nearest-even
  return (u16)(u >> 16);
}

// ---------------- init: zero per-expert counters ----------------
__global__ void init_kernel(int* counts) {
  if (threadIdx.x < NEXP) counts[threadIdx.x] = 0;
}

// ---------------- router: fp32 logits + group-limited top-4 ----------------
__global__ void router_kernel(const float* __restrict__ x, const float* __restrict__ Wg,
                              const float* __restrict__ bias,
                              int* __restrict__ topk_idx, float* __restrict__ topk_w,
                              int* __restrict__ counts, u16* __restrict__ Xbf) {
  int t = blockIdx.x;
  int lane = threadIdx.x;
  const float* xr = x + (size_t)t * HDIM;
  float acc[NEXP];
#pragma unroll
  for (int e = 0; e < NEXP; e++) acc[e] = 0.f;
  for (int h = lane; h < HDIM; h += 64) {
    float xv = xr[h];
    Xbf[(size_t)t * HDIM + h] = f2bf(xv);
#pragma unroll
    for (int e = 0; e < NEXP; e++) acc[e] += xv * Wg[e * HDIM + h];
  }
#pragma unroll
  for (int e = 0; e < NEXP; e++) {
    float v = acc[e];
#pragma unroll
    for (int off = 32; off > 0; off >>= 1) v += __shfl_down(v, off);
    acc[e] = v;
  }
  if (lane == 0) {
    float scores[NEXP], sc[NEXP];
#pragma unroll
    for (int e = 0; e < NEXP; e++) {
      float s = 1.f / (1.f + expf(-acc[e]));
      scores[e] = s;
      sc[e] = s + bias[e];
    }
    // group scores: sum of top-2 within each group of 4 consecutive experts
    float gsum[4];
#pragma unroll
    for (int g = 0; g < 4; g++) {
      float a = sc[4*g], b = sc[4*g+1], c = sc[4*g+2], d = sc[4*g+3];
      float hi1 = fmaxf(a, b), lo1 = fminf(a, b);
      float hi2 = fmaxf(c, d), lo2 = fminf(c, d);
      gsum[g] = fmaxf(hi1, hi2) + fmaxf(fminf(hi1, hi2), fmaxf(lo1, lo2));
    }
    // top-2 groups (first-occurrence tie-break, matches lax.top_k)
    int g0 = 0; float bv = gsum[0];
#pragma unroll
    for (int g = 1; g < 4; g++) if (gsum[g] > bv) { bv = gsum[g]; g0 = g; }
    int g1 = -1; float bv2 = -1e30f;
#pragma unroll
    for (int g = 0; g < 4; g++) if (g != g0 && gsum[g] > bv2) { bv2 = gsum[g]; g1 = g; }
    // masked scores (exact replication of jnp.where(smask>0, s_choice, 0.0))
    float m[NEXP];
#pragma unroll
    for (int e = 0; e < NEXP; e++) {
      int g = e >> 2;
      m[e] = (g == g0 || g == g1) ? sc[e] : 0.0f;
    }
    int idx[TOPK]; float w[TOPK];
#pragma unroll
    for (int k = 0; k < TOPK; k++) {
      int bj = 0; float bmv = m[0];
#pragma unroll
      for (int j = 1; j < NEXP; j++) if (m[j] > bmv) { bmv = m[j]; bj = j; }
      idx[k] = bj; w[k] = scores[bj];
#pragma unroll
      for (int j = 0; j < NEXP; j++) m[j] = (j == bj) ? -1e30f : m[j];
    }
    float s4 = w[0] + w[1] + w[2] + w[3] + 1e-20f;
    float inv = SCALE_F / s4;
#pragma unroll
    for (int k = 0; k < TOPK; k++) {
      topk_idx[t * TOPK + k] = idx[k];
      topk_w[t * TOPK + k] = w[k] * inv;
      atomicAdd(&counts[idx[k]], 1);
    }
  }
}

// ---------------- scan: per-expert offsets ----------------
__global__ void scan_kernel(const int* __restrict__ counts, int* __restrict__ offsets,
                            int* __restrict__ fill) {
  if (threadIdx.x == 0 && blockIdx.x == 0) {
    int s = 0;
    for (int e = 0; e < NEXP; e++) { offsets[e] = s; fill[e] = s; s += counts[e]; }
  }
}

// ---------------- scatter: build permuted slot lists ----------------
__global__ void scatter_kernel(const int* __restrict__ topk_idx, const float* __restrict__ topk_w,
                               int* __restrict__ fill, int* __restrict__ perm_token,
                               float* __restrict__ perm_w) {
  int j = blockIdx.x * blockDim.x + threadIdx.x;
  if (j < NSLOT) {
    int e = topk_idx[j];
    int pos = atomicAdd(&fill[e], 1);
    perm_token[pos] = j >> 2;
    perm_w[pos] = topk_w[j];
  }
}

// ---------------- fp32 -> bf16 conversion ----------------
__global__ void cvt_kernel(const float* __restrict__ src, u16* __restrict__ dst, int n4) {
  int i = blockIdx.x * 256 + threadIdx.x;
  if (i >= n4) return;
  float4 v = reinterpret_cast<const float4*>(src)[i];
  ushort4 o;
  o.x = f2bf(v.x); o.y = f2bf(v.y); o.z = f2bf(v.z); o.w = f2bf(v.w);
  reinterpret_cast<ushort4*>(dst)[i] = o;
}

// ---------------- NT GEMM: C[M,N] = A[M,K] @ B[N,K]^T (bf16 in, fp32 acc) ----------------
// EPI 0: relu2 * rowscale -> bf16 (permuted rows)   [routed up]
// EPI 1: relu2 -> bf16                              [shared up]
// EPI 2: fp32 store                                 [shared down]
// EPI 3: fp32 atomicAdd at rowmapOut[row]           [routed down]
#define BM 64
#define BN 64
#define BK 32
#define LDST 40   // padded LDS row stride (bf16 elems): breaks pow2 bank conflicts

template<int EPI>
__global__ void __launch_bounds__(256) gemm_nt(
    const u16* __restrict__ A, const u16* __restrict__ B,
    int K, int N,
    const int* __restrict__ eoffs, const int* __restrict__ ecnts, int Mfull,
    size_t strideB,
    const int* __restrict__ rowmapA,
    u16* __restrict__ Cb, float* __restrict__ Cf,
    const float* __restrict__ rowscale, const int* __restrict__ rowmapOut)
{
  int e = blockIdx.z;
  int rowbase = eoffs ? eoffs[e] : 0;
  int Mloc = ecnts ? ecnts[e] : Mfull;
  int m0 = blockIdx.x * BM;
  if (m0 >= Mloc) return;
  int n0 = blockIdx.y * BN;
  const u16* Bp = B + (size_t)e * strideB;

  __shared__ __align__(16) u16 sA[BM * LDST];
  __shared__ __align__(16) u16 sB[BN * LDST];

  int tid = threadIdx.x;
  int lane = tid & 63;
  int wave = tid >> 6;
  int wm = (wave >> 1) * 32;
  int wn = (wave & 1) * 32;
  int fm = lane & 15;
  int kq = lane >> 4;

  int srow = tid >> 2;          // staging row 0..63
  int scol = (tid & 3) * 8;     // staging k-offset {0,8,16,24}

  int arow = m0 + srow;
  bool aval = arow < Mloc;
  const u16* Arow;
  if (rowmapA) {
    int tok = 0;
    if (aval) tok = rowmapA[rowbase + arow];
    Arow = A + (size_t)tok * K;
  } else {
    Arow = A + (size_t)(rowbase + (aval ? arow : m0)) * K;
  }
  const u16* Brow = Bp + (size_t)(n0 + srow) * K;

  f32x4 acc[2][2];
#pragma unroll
  for (int i = 0; i < 2; i++)
#pragma unroll
    for (int j = 0; j < 2; j++) acc[i][j] = (f32x4){0.f, 0.f, 0.f, 0.f};

  for (int k0 = 0; k0 < K; k0 += BK) {
    uint4 av = make_uint4(0u, 0u, 0u, 0u);
    if (aval) av = *reinterpret_cast<const uint4*>(Arow + k0 + scol);
    uint4 bv = *reinterpret_cast<const uint4*>(Brow + k0 + scol);
    *reinterpret_cast<uint4*>(&sA[srow * LDST + scol]) = av;
    *reinterpret_cast<uint4*>(&sB[srow * LDST + scol]) = bv;
    __syncthreads();
    u16x8 a0 = *reinterpret_cast<const u16x8*>(&sA[(wm + fm) * LDST + kq * 8]);
    u16x8 a1 = *reinterpret_cast<const u16x8*>(&sA[(wm + 16 + fm) * LDST + kq * 8]);
    u16x8 b0 = *reinterpret_cast<const u16x8*>(&sB[(wn + fm) * LDST + kq * 8]);
    u16x8 b1 = *reinterpret_cast<const u16x8*>(&sB[(wn + 16 + fm) * LDST + kq * 8]);
    acc[0][0] = __builtin_amdgcn_mfma_f32_16x16x32_bf16(__builtin_bit_cast(bf16x8, a0), __builtin_bit_cast(bf16x8, b0), acc[0][0], 0, 0, 0);
    acc[0][1] = __builtin_amdgcn_mfma_f32_16x16x32_bf16(__builtin_bit_cast(bf16x8, a0), __builtin_bit_cast(bf16x8, b1), acc[0][1], 0, 0, 0);
    acc[1][0] = __builtin_amdgcn_mfma_f32_16x16x32_bf16(__builtin_bit_cast(bf16x8, a1), __builtin_bit_cast(bf16x8, b0), acc[1][0], 0, 0, 0);
    acc[1][1] = __builtin_amdgcn_mfma_f32_16x16x32_bf16(__builtin_bit_cast(bf16x8, a1), __builtin_bit_cast(bf16x8, b1), acc[1][1], 0, 0, 0);
    __syncthreads();
  }

  // epilogue: C/D mapping col = lane&15, row = (lane>>4)*4 + reg  (verified m89/m91)
#pragma unroll
  for (int mt = 0; mt < 2; mt++) {
#pragma unroll
    for (int nt = 0; nt < 2; nt++) {
      int gn = n0 + wn + nt * 16 + fm;
      f32x4 a = acc[mt][nt];
#pragma unroll
      for (int r = 0; r < 4; r++) {
        int gm = m0 + wm + mt * 16 + kq * 4 + r;
        if (gm < Mloc) {
          float v = a[r];
          if (EPI == 0) {
            float tq = fmaxf(v, 0.f);
            tq = tq * tq * rowscale[rowbase + gm];
            Cb[(size_t)(rowbase + gm) * N + gn] = f2bf(tq);
          } else if (EPI == 1) {
            float tq = fmaxf(v, 0.f);
            Cb[(size_t)gm * N + gn] = f2bf(tq * tq);
          } else if (EPI == 2) {
            Cf[(size_t)gm * N + gn] = v;
          } else {
            atomicAdd(Cf + (size_t)rowmapOut[rowbase + gm] * N + gn, v);
          }
        }
      }
    }
  }
}

// ---------------- launcher ----------------
extern "C" void kernel_launch(void* const* d_in, const int* in_sizes, int n_in,
                              void* d_out, int out_size, void* d_ws, size_t ws_size,
                              hipStream_t stream) {
  const float* x    = (const float*)d_in[0];
  const float* Wg   = (const float*)d_in[1];
  const float* bias = (const float*)d_in[2];
  const float* W1   = (const float*)d_in[3];
  const float* W2   = (const float*)d_in[4];
  const float* Ws1  = (const float*)d_in[5];
  const float* Ws2  = (const float*)d_in[6];
  float* out = (float*)d_out;

  char* p = (char*)d_ws;
  auto alloc = [&](size_t bytes) -> void* {
    void* r = (void*)p;
    p += (bytes + 255) & ~(size_t)255;
    return r;
  };
  int*   topk_idx   = (int*)  alloc((size_t)NSLOT * 4);
  float* topk_w     = (float*)alloc((size_t)NSLOT * 4);
  int*   counts     = (int*)  alloc(64);
  int*   offsets    = (int*)  alloc(64);
  int*   fill       = (int*)  alloc(64);
  int*   perm_token = (int*)  alloc((size_t)NSLOT * 4);
  float* perm_w     = (float*)alloc((size_t)NSLOT * 4);
  u16*   Xbf        = (u16*)  alloc((size_t)T_TOK * HDIM * 2);
  u16*   W1b        = (u16*)  alloc((size_t)NEXP * IDIM * HDIM * 2);
  u16*   W2b        = (u16*)  alloc((size_t)NEXP * HDIM * IDIM * 2);
  u16*   Ws1b       = (u16*)  alloc((size_t)ISDIM * HDIM * 2);
  u16*   Ws2b       = (u16*)  alloc((size_t)HDIM * ISDIM * 2);
  u16*   Hg         = (u16*)  alloc((size_t)NSLOT * IDIM * 2);
  u16*   Hs         = (u16*)  alloc((size_t)T_TOK * ISDIM * 2);

  init_kernel<<<1, 64, 0, stream>>>(counts);
  router_kernel<<<T_TOK, 64, 0, stream>>>(x, Wg, bias, topk_idx, topk_w, counts, Xbf);
  scan_kernel<<<1, 1, 0, stream>>>(counts, offsets, fill);

  {
    int n4 = NEXP * IDIM * HDIM / 4;
    cvt_kernel<<<(n4 + 255) / 256, 256, 0, stream>>>(W1, W1b, n4);
    cvt_kernel<<<(n4 + 255) / 256, 256, 0, stream>>>(W2, W2b, n4);
    int n4s = ISDIM * HDIM / 4;
    cvt_kernel<<<(n4s + 255) / 256, 256, 0, stream>>>(Ws1, Ws1b, n4s);
    cvt_kernel<<<(n4s + 255) / 256, 256, 0, stream>>>(Ws2, Ws2b, n4s);
  }

  scatter_kernel<<<(NSLOT + 255) / 256, 256, 0, stream>>>(topk_idx, topk_w, fill,
                                                          perm_token, perm_w);

  // routed up: Hg[slot, I] = perm_w * relu2(x[tok] @ W1[e]^T)
  gemm_nt<0><<<dim3(T_TOK / BM, IDIM / BN, NEXP), 256, 0, stream>>>(
      Xbf, W1b, HDIM, IDIM, offsets, counts, 0, (size_t)IDIM * HDIM,
      perm_token, Hg, nullptr, perm_w, nullptr);

  // shared up: Hs = relu2(x @ Ws1^T)
  gemm_nt<1><<<dim3(T_TOK / BM, ISDIM / BN, 1), 256, 0, stream>>>(
      Xbf, Ws1b, HDIM, ISDIM, nullptr, nullptr, T_TOK, 0,
      nullptr, Hs, nullptr, nullptr, nullptr);

  // shared down: out = Hs @ Ws2^T  (full fp32 store, runs before routed atomics)
  gemm_nt<2><<<dim3(T_TOK / BM, HDIM / BN, 1), 256, 0, stream>>>(
      Hs, Ws2b, ISDIM, HDIM, nullptr, nullptr, T_TOK, 0,
      nullptr, nullptr, out, nullptr, nullptr);

  // routed down: out[tok] += Hg[slot] @ W2[e]^T  (fp32 atomics)
  gemm_nt<3><<<dim3(T_TOK / BM, HDIM / BN, NEXP), 256, 0, stream>>>(
      Hg, W2b, IDIM, HDIM, offsets, counts, 0, (size_t)HDIM * IDIM,
      nullptr, nullptr, out, nullptr, perm_token);
}

// Round 2
// 463.189 us; speedup vs baseline: 1.0184x; 1.0184x over previous
//
#include <hip/hip_runtime.h>
#include <hip/hip_bf16.h>

#define T_TOK 2048
#define HDIM 1024
#define IDIM 512
#define ISDIM 1024
#define NEXP 16
#define TOPK 4
#define NSLOT (T_TOK*TOPK)
#define SCALE_F 2.5f

typedef unsigned short u16;
typedef float f32x4 __attribute__((ext_vector_type(4)));
typedef __bf16 bf16x8 __attribute__((ext_vector_type(8)));
typedef u16 u16x8 __attribute__((ext_vector_type(8)));

__device__ __forceinline__ u16 f2bf(float f) {
  unsigned u = __builtin_bit_cast(unsigned, f);
  u += 0x7fffu + ((u >> 16) & 1u);   // round-to-nearest-even
  return (u16)(u >> 16);
}

// ---------------- init: zero per-expert counters ----------------
__global__ void init_kernel(int* counts) {
  if (threadIdx.x < NEXP) counts[threadIdx.x] = 0;
}

// ---------------- router v2: 256 threads/token, float4 dots, LDS combine ----
// Round-1 version was latency-bound (32 VGPRs, serialized scalar Wg loads,
// 114 us). Here: 1 float4/thread stages the token, each wave does 4 experts
// with 16 independent float4 loads/lane -> full ILP, then shfl_xor reduce.
__global__ void __launch_bounds__(256) router_kernel(
    const float* __restrict__ x, const float* __restrict__ Wg,
    const float* __restrict__ bias,
    int* __restrict__ topk_idx, float* __restrict__ topk_w,
    int* __restrict__ counts, u16* __restrict__ Xbf) {
  int t = blockIdx.x;
  int tid = threadIdx.x;
  int lane = tid & 63;
  int wave = tid >> 6;

  __shared__ __align__(16) float sx[HDIM];
  __shared__ float ssc[NEXP];

  // stage x into LDS (fp32) and emit bf16 copy: one float4 per thread
  float4 xv = reinterpret_cast<const float4*>(x + (size_t)t * HDIM)[tid];
  reinterpret_cast<float4*>(sx)[tid] = xv;
  ushort4 o;
  o.x = f2bf(xv.x); o.y = f2bf(xv.y); o.z = f2bf(xv.z); o.w = f2bf(xv.w);
  reinterpret_cast<ushort4*>(Xbf + (size_t)t * HDIM)[tid] = o;
  __syncthreads();

  // wave w computes experts 4w..4w+3; each lane covers 16 h-elements x 4 chunks
  float acc[4] = {0.f, 0.f, 0.f, 0.f};
  const float4* sx4 = reinterpret_cast<const float4*>(sx);
#pragma unroll
  for (int c = 0; c < 4; c++) {
    float4 xq = sx4[lane + 64 * c];
#pragma unroll
    for (int e = 0; e < 4; e++) {
      float4 wq = reinterpret_cast<const float4*>(
          Wg + (size_t)(wave * 4 + e) * HDIM)[lane + 64 * c];
      acc[e] += xq.x * wq.x + xq.y * wq.y + xq.z * wq.z + xq.w * wq.w;
    }
  }
#pragma unroll
  for (int e = 0; e < 4; e++) {
    float v = acc[e];
#pragma unroll
    for (int off = 32; off > 0; off >>= 1) v += __shfl_xor(v, off);
    if (lane == 0) ssc[wave * 4 + e] = v;
  }
  __syncthreads();

  if (tid == 0) {
    float scores[NEXP], sc[NEXP];
#pragma unroll
    for (int e = 0; e < NEXP; e++) {
      float s = 1.f / (1.f + expf(-ssc[e]));
      scores[e] = s;
      sc[e] = s + bias[e];
    }
    // group scores: sum of top-2 within each group of 4 consecutive experts
    float gsum[4];
#pragma unroll
    for (int g = 0; g < 4; g++) {
      float a = sc[4*g], b = sc[4*g+1], c = sc[4*g+2], d = sc[4*g+3];
      float hi1 = fmaxf(a, b), lo1 = fminf(a, b);
      float hi2 = fmaxf(c, d), lo2 = fminf(c, d);
      gsum[g] = fmaxf(hi1, hi2) + fmaxf(fminf(hi1, hi2), fmaxf(lo1, lo2));
    }
    // top-2 groups (first-occurrence tie-break, matches lax.top_k)
    int g0 = 0; float bv = gsum[0];
#pragma unroll
    for (int g = 1; g < 4; g++) if (gsum[g] > bv) { bv = gsum[g]; g0 = g; }
    int g1 = -1; float bv2 = -1e30f;
#pragma unroll
    for (int g = 0; g < 4; g++) if (g != g0 && gsum[g] > bv2) { bv2 = gsum[g]; g1 = g; }
    float m[NEXP];
#pragma unroll
    for (int e = 0; e < NEXP; e++) {
      int g = e >> 2;
      m[e] = (g == g0 || g == g1) ? sc[e] : 0.0f;
    }
    int idx[TOPK]; float w[TOPK];
#pragma unroll
    for (int k = 0; k < TOPK; k++) {
      int bj = 0; float bmv = m[0];
#pragma unroll
      for (int j = 1; j < NEXP; j++) if (m[j] > bmv) { bmv = m[j]; bj = j; }
      idx[k] = bj; w[k] = scores[bj];
#pragma unroll
      for (int j = 0; j < NEXP; j++) m[j] = (j == bj) ? -1e30f : m[j];
    }
    float s4 = w[0] + w[1] + w[2] + w[3] + 1e-20f;
    float inv = SCALE_F / s4;
#pragma unroll
    for (int k = 0; k < TOPK; k++) {
      topk_idx[t * TOPK + k] = idx[k];
      topk_w[t * TOPK + k] = w[k] * inv;
      atomicAdd(&counts[idx[k]], 1);
    }
  }
}

// ---------------- scan: per-expert offsets ----------------
__global__ void scan_kernel(const int* __restrict__ counts, int* __restrict__ offsets,
                            int* __restrict__ fill) {
  if (threadIdx.x == 0 && blockIdx.x == 0) {
    int s = 0;
    for (int e = 0; e < NEXP; e++) { offsets[e] = s; fill[e] = s; s += counts[e]; }
  }
}

// ---------------- scatter: build permuted slot lists ----------------
__global__ void scatter_kernel(const int* __restrict__ topk_idx, const float* __restrict__ topk_w,
                               int* __restrict__ fill, int* __restrict__ perm_token,
                               float* __restrict__ perm_w) {
  int j = blockIdx.x * blockDim.x + threadIdx.x;
  if (j < NSLOT) {
    int e = topk_idx[j];
    int pos = atomicAdd(&fill[e], 1);
    perm_token[pos] = j >> 2;
    perm_w[pos] = topk_w[j];
  }
}

// ---------------- fp32 -> bf16 conversion ----------------
__global__ void cvt_kernel(const float* __restrict__ src, u16* __restrict__ dst, int n4) {
  int i = blockIdx.x * 256 + threadIdx.x;
  if (i >= n4) return;
  float4 v = reinterpret_cast<const float4*>(src)[i];
  ushort4 o;
  o.x = f2bf(v.x); o.y = f2bf(v.y); o.z = f2bf(v.z); o.w = f2bf(v.w);
  reinterpret_cast<ushort4*>(dst)[i] = o;
}

// ---------------- NT GEMM: C[M,N] = A[M,K] @ B[N,K]^T (bf16 in, fp32 acc) ----------------
// EPI 0: relu2 * rowscale -> bf16 (permuted rows)   [routed up]
// EPI 1: relu2 -> bf16                              [shared up]
// EPI 2: fp32 store                                 [shared down]
// EPI 3: fp32 atomicAdd at rowmapOut[row]           [routed down]
#define BM 64
#define BN 64
#define BK 32
#define LDST 40   // padded LDS row stride (bf16 elems): breaks pow2 bank conflicts

template<int EPI>
__global__ void __launch_bounds__(256) gemm_nt(
    const u16* __restrict__ A, const u16* __restrict__ B,
    int K, int N,
    const int* __restrict__ eoffs, const int* __restrict__ ecnts, int Mfull,
    size_t strideB,
    const int* __restrict__ rowmapA,
    u16* __restrict__ Cb, float* __restrict__ Cf,
    const float* __restrict__ rowscale, const int* __restrict__ rowmapOut)
{
  int e = blockIdx.z;
  int rowbase = eoffs ? eoffs[e] : 0;
  int Mloc = ecnts ? ecnts[e] : Mfull;
  int m0 = blockIdx.x * BM;
  if (m0 >= Mloc) return;
  int n0 = blockIdx.y * BN;
  const u16* Bp = B + (size_t)e * strideB;

  __shared__ __align__(16) u16 sA[BM * LDST];
  __shared__ __align__(16) u16 sB[BN * LDST];

  int tid = threadIdx.x;
  int lane = tid & 63;
  int wave = tid >> 6;
  int wm = (wave >> 1) * 32;
  int wn = (wave & 1) * 32;
  int fm = lane & 15;
  int kq = lane >> 4;

  int srow = tid >> 2;          // staging row 0..63
  int scol = (tid & 3) * 8;     // staging k-offset {0,8,16,24}

  int arow = m0 + srow;
  bool aval = arow < Mloc;
  const u16* Arow;
  if (rowmapA) {
    int tok = 0;
    if (aval) tok = rowmapA[rowbase + arow];
    Arow = A + (size_t)tok * K;
  } else {
    Arow = A + (size_t)(rowbase + (aval ? arow : m0)) * K;
  }
  const u16* Brow = Bp + (size_t)(n0 + srow) * K;

  f32x4 acc[2][2];
#pragma unroll
  for (int i = 0; i < 2; i++)
#pragma unroll
    for (int j = 0; j < 2; j++) acc[i][j] = (f32x4){0.f, 0.f, 0.f, 0.f};

  for (int k0 = 0; k0 < K; k0 += BK) {
    uint4 av = make_uint4(0u, 0u, 0u, 0u);
    if (aval) av = *reinterpret_cast<const uint4*>(Arow + k0 + scol);
    uint4 bv = *reinterpret_cast<const uint4*>(Brow + k0 + scol);
    *reinterpret_cast<uint4*>(&sA[srow * LDST + scol]) = av;
    *reinterpret_cast<uint4*>(&sB[srow * LDST + scol]) = bv;
    __syncthreads();
    u16x8 a0 = *reinterpret_cast<const u16x8*>(&sA[(wm + fm) * LDST + kq * 8]);
    u16x8 a1 = *reinterpret_cast<const u16x8*>(&sA[(wm + 16 + fm) * LDST + kq * 8]);
    u16x8 b0 = *reinterpret_cast<const u16x8*>(&sB[(wn + fm) * LDST + kq * 8]);
    u16x8 b1 = *reinterpret_cast<const u16x8*>(&sB[(wn + 16 + fm) * LDST + kq * 8]);
    acc[0][0] = __builtin_amdgcn_mfma_f32_16x16x32_bf16(__builtin_bit_cast(bf16x8, a0), __builtin_bit_cast(bf16x8, b0), acc[0][0], 0, 0, 0);
    acc[0][1] = __builtin_amdgcn_mfma_f32_16x16x32_bf16(__builtin_bit_cast(bf16x8, a0), __builtin_bit_cast(bf16x8, b1), acc[0][1], 0, 0, 0);
    acc[1][0] = __builtin_amdgcn_mfma_f32_16x16x32_bf16(__builtin_bit_cast(bf16x8, a1), __builtin_bit_cast(bf16x8, b0), acc[1][0], 0, 0, 0);
    acc[1][1] = __builtin_amdgcn_mfma_f32_16x16x32_bf16(__builtin_bit_cast(bf16x8, a1), __builtin_bit_cast(bf16x8, b1), acc[1][1], 0, 0, 0);
    __syncthreads();
  }

  // epilogue: C/D mapping col = lane&15, row = (lane>>4)*4 + reg  (verified m89/m91)
#pragma unroll
  for (int mt = 0; mt < 2; mt++) {
#pragma unroll
    for (int nt = 0; nt < 2; nt++) {
      int gn = n0 + wn + nt * 16 + fm;
      f32x4 a = acc[mt][nt];
#pragma unroll
      for (int r = 0; r < 4; r++) {
        int gm = m0 + wm + mt * 16 + kq * 4 + r;
        if (gm < Mloc) {
          float v = a[r];
          if (EPI == 0) {
            float tq = fmaxf(v, 0.f);
            tq = tq * tq * rowscale[rowbase + gm];
            Cb[(size_t)(rowbase + gm) * N + gn] = f2bf(tq);
          } else if (EPI == 1) {
            float tq = fmaxf(v, 0.f);
            Cb[(size_t)gm * N + gn] = f2bf(tq * tq);
          } else if (EPI == 2) {
            Cf[(size_t)gm * N + gn] = v;
          } else {
            atomicAdd(Cf + (size_t)rowmapOut[rowbase + gm] * N + gn, v);
          }
        }
      }
    }
  }
}

// ---------------- launcher ----------------
extern "C" void kernel_launch(void* const* d_in, const int* in_sizes, int n_in,
                              void* d_out, int out_size, void* d_ws, size_t ws_size,
                              hipStream_t stream) {
  const float* x    = (const float*)d_in[0];
  const float* Wg   = (const float*)d_in[1];
  const float* bias = (const float*)d_in[2];
  const float* W1   = (const float*)d_in[3];
  const float* W2   = (const float*)d_in[4];
  const float* Ws1  = (const float*)d_in[5];
  const float* Ws2  = (const float*)d_in[6];
  float* out = (float*)d_out;

  char* p = (char*)d_ws;
  auto alloc = [&](size_t bytes) -> void* {
    void* r = (void*)p;
    p += (bytes + 255) & ~(size_t)255;
    return r;
  };
  int*   topk_idx   = (int*)  alloc((size_t)NSLOT * 4);
  float* topk_w     = (float*)alloc((size_t)NSLOT * 4);
  int*   counts     = (int*)  alloc(64);
  int*   offsets    = (int*)  alloc(64);
  int*   fill       = (int*)  alloc(64);
  int*   perm_token = (int*)  alloc((size_t)NSLOT * 4);
  float* perm_w     = (float*)alloc((size_t)NSLOT * 4);
  u16*   Xbf        = (u16*)  alloc((size_t)T_TOK * HDIM * 2);
  u16*   W1b        = (u16*)  alloc((size_t)NEXP * IDIM * HDIM * 2);
  u16*   W2b        = (u16*)  alloc((size_t)NEXP * HDIM * IDIM * 2);
  u16*   Ws1b       = (u16*)  alloc((size_t)ISDIM * HDIM * 2);
  u16*   Ws2b       = (u16*)  alloc((size_t)HDIM * ISDIM * 2);
  u16*   Hg         = (u16*)  alloc((size_t)NSLOT * IDIM * 2);
  u16*   Hs         = (u16*)  alloc((size_t)T_TOK * ISDIM * 2);

  init_kernel<<<1, 64, 0, stream>>>(counts);
  router_kernel<<<T_TOK, 256, 0, stream>>>(x, Wg, bias, topk_idx, topk_w, counts, Xbf);
  scan_kernel<<<1, 1, 0, stream>>>(counts, offsets, fill);

  {
    int n4 = NEXP * IDIM * HDIM / 4;
    cvt_kernel<<<(n4 + 255) / 256, 256, 0, stream>>>(W1, W1b, n4);
    cvt_kernel<<<(n4 + 255) / 256, 256, 0, stream>>>(W2, W2b, n4);
    int n4s = ISDIM * HDIM / 4;
    cvt_kernel<<<(n4s + 255) / 256, 256, 0, stream>>>(Ws1, Ws1b, n4s);
    cvt_kernel<<<(n4s + 255) / 256, 256, 0, stream>>>(Ws2, Ws2b, n4s);
  }

  scatter_kernel<<<(NSLOT + 255) / 256, 256, 0, stream>>>(topk_idx, topk_w, fill,
                                                          perm_token, perm_w);

  // routed up: Hg[slot, I] = perm_w * relu2(x[tok] @ W1[e]^T)
  gemm_nt<0><<<dim3(T_TOK / BM, IDIM / BN, NEXP), 256, 0, stream>>>(
      Xbf, W1b, HDIM, IDIM, offsets, counts, 0, (size_t)IDIM * HDIM,
      perm_token, Hg, nullptr, perm_w, nullptr);

  // shared up: Hs = relu2(x @ Ws1^T)
  gemm_nt<1><<<dim3(T_TOK / BM, ISDIM / BN, 1), 256, 0, stream>>>(
      Xbf, Ws1b, HDIM, ISDIM, nullptr, nullptr, T_TOK, 0,
      nullptr, Hs, nullptr, nullptr, nullptr);

  // shared down: out = Hs @ Ws2^T  (full fp32 store, runs before routed atomics)
  gemm_nt<2><<<dim3(T_TOK / BM, HDIM / BN, 1), 256, 0, stream>>>(
      Hs, Ws2b, ISDIM, HDIM, nullptr, nullptr, T_TOK, 0,
      nullptr, nullptr, out, nullptr, nullptr);

  // routed down: out[tok] += Hg[slot] @ W2[e]^T  (fp32 atomics)
  gemm_nt<3><<<dim3(T_TOK / BM, HDIM / BN, NEXP), 256, 0, stream>>>(
      Hg, W2b, IDIM, HDIM, offsets, counts, 0, (size_t)HDIM * IDIM,
      nullptr, nullptr, out, nullptr, perm_token);
}

// Round 3
// 368.732 us; speedup vs baseline: 1.2792x; 1.2562x over previous
//
#include <hip/hip_runtime.h>
#include <hip/hip_bf16.h>

#define T_TOK 2048
#define HDIM 1024
#define IDIM 512
#define ISDIM 1024
#define NEXP 16
#define TOPK 4
#define NSLOT (T_TOK*TOPK)
#define SCALE_F 2.5f

typedef unsigned short u16;
typedef float f32x4 __attribute__((ext_vector_type(4)));
typedef __bf16 bf16x8 __attribute__((ext_vector_type(8)));
typedef u16 u16x8 __attribute__((ext_vector_type(8)));

__device__ __forceinline__ u16 f2bf(float f) {
  unsigned u = __builtin_bit_cast(unsigned, f);
  u += 0x7fffu + ((u >> 16) & 1u);   // round-to-nearest-even
  return (u16)(u >> 16);
}

// ---------------- router v3: NO global atomics ----------------
// R1 (64thr, serial loads) = 114us; R2 (256thr, float4 ILP) = 102us with
// VALUBusy 4% -> the invariant cost was 8192 contended atomicAdds to one
// 64B line (counts[16]) across 2048 blocks / 8 XCDs. v3 only writes
// topk_idx/topk_w; counting moved to route_build.
__global__ void __launch_bounds__(256) router_kernel(
    const float* __restrict__ x, const float* __restrict__ Wg,
    const float* __restrict__ bias,
    int* __restrict__ topk_idx, float* __restrict__ topk_w,
    u16* __restrict__ Xbf) {
  int t = blockIdx.x;
  int tid = threadIdx.x;
  int lane = tid & 63;
  int wave = tid >> 6;

  __shared__ __align__(16) float sx[HDIM];
  __shared__ float ssc[NEXP];

  // stage x into LDS (fp32) and emit bf16 copy: one float4 per thread
  float4 xv = reinterpret_cast<const float4*>(x + (size_t)t * HDIM)[tid];
  reinterpret_cast<float4*>(sx)[tid] = xv;
  ushort4 o;
  o.x = f2bf(xv.x); o.y = f2bf(xv.y); o.z = f2bf(xv.z); o.w = f2bf(xv.w);
  reinterpret_cast<ushort4*>(Xbf + (size_t)t * HDIM)[tid] = o;
  __syncthreads();

  // wave w computes experts 4w..4w+3; each lane covers 4 float4 chunks
  float acc[4] = {0.f, 0.f, 0.f, 0.f};
  const float4* sx4 = reinterpret_cast<const float4*>(sx);
#pragma unroll
  for (int c = 0; c < 4; c++) {
    float4 xq = sx4[lane + 64 * c];
#pragma unroll
    for (int e = 0; e < 4; e++) {
      float4 wq = reinterpret_cast<const float4*>(
          Wg + (size_t)(wave * 4 + e) * HDIM)[lane + 64 * c];
      acc[e] += xq.x * wq.x + xq.y * wq.y + xq.z * wq.z + xq.w * wq.w;
    }
  }
#pragma unroll
  for (int e = 0; e < 4; e++) {
    float v = acc[e];
#pragma unroll
    for (int off = 32; off > 0; off >>= 1) v += __shfl_xor(v, off);
    if (lane == 0) ssc[wave * 4 + e] = v;
  }
  __syncthreads();

  if (tid == 0) {
    float scores[NEXP], sc[NEXP];
#pragma unroll
    for (int e = 0; e < NEXP; e++) {
      float s = 1.f / (1.f + expf(-ssc[e]));
      scores[e] = s;
      sc[e] = s + bias[e];
    }
    // group scores: sum of top-2 within each group of 4 consecutive experts
    float gsum[4];
#pragma unroll
    for (int g = 0; g < 4; g++) {
      float a = sc[4*g], b = sc[4*g+1], c = sc[4*g+2], d = sc[4*g+3];
      float hi1 = fmaxf(a, b), lo1 = fminf(a, b);
      float hi2 = fmaxf(c, d), lo2 = fminf(c, d);
      gsum[g] = fmaxf(hi1, hi2) + fmaxf(fminf(hi1, hi2), fmaxf(lo1, lo2));
    }
    // top-2 groups (first-occurrence tie-break, matches lax.top_k)
    int g0 = 0; float bv = gsum[0];
#pragma unroll
    for (int g = 1; g < 4; g++) if (gsum[g] > bv) { bv = gsum[g]; g0 = g; }
    int g1 = -1; float bv2 = -1e30f;
#pragma unroll
    for (int g = 0; g < 4; g++) if (g != g0 && gsum[g] > bv2) { bv2 = gsum[g]; g1 = g; }
    float m[NEXP];
#pragma unroll
    for (int e = 0; e < NEXP; e++) {
      int g = e >> 2;
      m[e] = (g == g0 || g == g1) ? sc[e] : 0.0f;
    }
    int idx[TOPK]; float w[TOPK];
#pragma unroll
    for (int k = 0; k < TOPK; k++) {
      int bj = 0; float bmv = m[0];
#pragma unroll
      for (int j = 1; j < NEXP; j++) if (m[j] > bmv) { bmv = m[j]; bj = j; }
      idx[k] = bj; w[k] = scores[bj];
#pragma unroll
      for (int j = 0; j < NEXP; j++) m[j] = (j == bj) ? -1e30f : m[j];
    }
    float s4 = w[0] + w[1] + w[2] + w[3] + 1e-20f;
    float inv = SCALE_F / s4;
#pragma unroll
    for (int k = 0; k < TOPK; k++) {
      topk_idx[t * TOPK + k] = idx[k];
      topk_w[t * TOPK + k] = w[k] * inv;
    }
  }
}

// ---------------- route_build: histogram + scan + scatter, ONE block ------
// Replaces init/scan/scatter. LDS atomics only (16 distinct banks, per-CU
// pipe) -> no cross-XCD line ping-pong. Slot order within an expert is
// irrelevant to the final sum.
__global__ void __launch_bounds__(256) route_build(
    const int* __restrict__ topk_idx, const float* __restrict__ topk_w,
    int* __restrict__ offsets, int* __restrict__ counts,
    int* __restrict__ perm_token, float* __restrict__ perm_w) {
  __shared__ int hcnt[NEXP];
  __shared__ int hfill[NEXP];
  int tid = threadIdx.x;
  if (tid < NEXP) hcnt[tid] = 0;
  __syncthreads();

  int e_loc[NSLOT / 256];
#pragma unroll
  for (int i = 0; i < NSLOT / 256; i++) {
    int j = tid + 256 * i;
    int e = topk_idx[j];
    e_loc[i] = e;
    atomicAdd(&hcnt[e], 1);
  }
  __syncthreads();

  if (tid == 0) {
    int s = 0;
#pragma unroll
    for (int e = 0; e < NEXP; e++) {
      int c = hcnt[e];
      offsets[e] = s;
      counts[e] = c;
      hfill[e] = s;
      s += c;
    }
  }
  __syncthreads();

#pragma unroll
  for (int i = 0; i < NSLOT / 256; i++) {
    int j = tid + 256 * i;
    int pos = atomicAdd(&hfill[e_loc[i]], 1);
    perm_token[pos] = j >> 2;
    perm_w[pos] = topk_w[j];
  }
}

// ---------------- fp32 -> bf16 conversion ----------------
__global__ void cvt_kernel(const float* __restrict__ src, u16* __restrict__ dst, int n4) {
  int i = blockIdx.x * 256 + threadIdx.x;
  if (i >= n4) return;
  float4 v = reinterpret_cast<const float4*>(src)[i];
  ushort4 o;
  o.x = f2bf(v.x); o.y = f2bf(v.y); o.z = f2bf(v.z); o.w = f2bf(v.w);
  reinterpret_cast<ushort4*>(dst)[i] = o;
}

// ---------------- NT GEMM: C[M,N] = A[M,K] @ B[N,K]^T (bf16 in, fp32 acc) ----------------
// EPI 0: relu2 * rowscale -> bf16 (permuted rows)   [routed up]
// EPI 1: relu2 -> bf16                              [shared up]
// EPI 2: fp32 store                                 [shared down]
// EPI 3: fp32 atomicAdd at rowmapOut[row]           [routed down]
#define BM 64
#define BN 64
#define BK 32
#define LDST 40   // padded LDS row stride (bf16 elems): breaks pow2 bank conflicts

template<int EPI>
__global__ void __launch_bounds__(256) gemm_nt(
    const u16* __restrict__ A, const u16* __restrict__ B,
    int K, int N,
    const int* __restrict__ eoffs, const int* __restrict__ ecnts, int Mfull,
    size_t strideB,
    const int* __restrict__ rowmapA,
    u16* __restrict__ Cb, float* __restrict__ Cf,
    const float* __restrict__ rowscale, const int* __restrict__ rowmapOut)
{
  int e = blockIdx.z;
  int rowbase = eoffs ? eoffs[e] : 0;
  int Mloc = ecnts ? ecnts[e] : Mfull;
  int m0 = blockIdx.x * BM;
  if (m0 >= Mloc) return;
  int n0 = blockIdx.y * BN;
  const u16* Bp = B + (size_t)e * strideB;

  __shared__ __align__(16) u16 sA[BM * LDST];
  __shared__ __align__(16) u16 sB[BN * LDST];

  int tid = threadIdx.x;
  int lane = tid & 63;
  int wave = tid >> 6;
  int wm = (wave >> 1) * 32;
  int wn = (wave & 1) * 32;
  int fm = lane & 15;
  int kq = lane >> 4;

  int srow = tid >> 2;          // staging row 0..63
  int scol = (tid & 3) * 8;     // staging k-offset {0,8,16,24}

  int arow = m0 + srow;
  bool aval = arow < Mloc;
  const u16* Arow;
  if (rowmapA) {
    int tok = 0;
    if (aval) tok = rowmapA[rowbase + arow];
    Arow = A + (size_t)tok * K;
  } else {
    Arow = A + (size_t)(rowbase + (aval ? arow : m0)) * K;
  }
  const u16* Brow = Bp + (size_t)(n0 + srow) * K;

  f32x4 acc[2][2];
#pragma unroll
  for (int i = 0; i < 2; i++)
#pragma unroll
    for (int j = 0; j < 2; j++) acc[i][j] = (f32x4){0.f, 0.f, 0.f, 0.f};

  for (int k0 = 0; k0 < K; k0 += BK) {
    uint4 av = make_uint4(0u, 0u, 0u, 0u);
    if (aval) av = *reinterpret_cast<const uint4*>(Arow + k0 + scol);
    uint4 bv = *reinterpret_cast<const uint4*>(Brow + k0 + scol);
    *reinterpret_cast<uint4*>(&sA[srow * LDST + scol]) = av;
    *reinterpret_cast<uint4*>(&sB[srow * LDST + scol]) = bv;
    __syncthreads();
    u16x8 a0 = *reinterpret_cast<const u16x8*>(&sA[(wm + fm) * LDST + kq * 8]);
    u16x8 a1 = *reinterpret_cast<const u16x8*>(&sA[(wm + 16 + fm) * LDST + kq * 8]);
    u16x8 b0 = *reinterpret_cast<const u16x8*>(&sB[(wn + fm) * LDST + kq * 8]);
    u16x8 b1 = *reinterpret_cast<const u16x8*>(&sB[(wn + 16 + fm) * LDST + kq * 8]);
    acc[0][0] = __builtin_amdgcn_mfma_f32_16x16x32_bf16(__builtin_bit_cast(bf16x8, a0), __builtin_bit_cast(bf16x8, b0), acc[0][0], 0, 0, 0);
    acc[0][1] = __builtin_amdgcn_mfma_f32_16x16x32_bf16(__builtin_bit_cast(bf16x8, a0), __builtin_bit_cast(bf16x8, b1), acc[0][1], 0, 0, 0);
    acc[1][0] = __builtin_amdgcn_mfma_f32_16x16x32_bf16(__builtin_bit_cast(bf16x8, a1), __builtin_bit_cast(bf16x8, b0), acc[1][0], 0, 0, 0);
    acc[1][1] = __builtin_amdgcn_mfma_f32_16x16x32_bf16(__builtin_bit_cast(bf16x8, a1), __builtin_bit_cast(bf16x8, b1), acc[1][1], 0, 0, 0);
    __syncthreads();
  }

  // epilogue: C/D mapping col = lane&15, row = (lane>>4)*4 + reg  (verified m89/m91)
#pragma unroll
  for (int mt = 0; mt < 2; mt++) {
#pragma unroll
    for (int nt = 0; nt < 2; nt++) {
      int gn = n0 + wn + nt * 16 + fm;
      f32x4 a = acc[mt][nt];
#pragma unroll
      for (int r = 0; r < 4; r++) {
        int gm = m0 + wm + mt * 16 + kq * 4 + r;
        if (gm < Mloc) {
          float v = a[r];
          if (EPI == 0) {
            float tq = fmaxf(v, 0.f);
            tq = tq * tq * rowscale[rowbase + gm];
            Cb[(size_t)(rowbase + gm) * N + gn] = f2bf(tq);
          } else if (EPI == 1) {
            float tq = fmaxf(v, 0.f);
            Cb[(size_t)gm * N + gn] = f2bf(tq * tq);
          } else if (EPI == 2) {
            Cf[(size_t)gm * N + gn] = v;
          } else {
            atomicAdd(Cf + (size_t)rowmapOut[rowbase + gm] * N + gn, v);
          }
        }
      }
    }
  }
}

// ---------------- launcher ----------------
extern "C" void kernel_launch(void* const* d_in, const int* in_sizes, int n_in,
                              void* d_out, int out_size, void* d_ws, size_t ws_size,
                              hipStream_t stream) {
  const float* x    = (const float*)d_in[0];
  const float* Wg   = (const float*)d_in[1];
  const float* bias = (const float*)d_in[2];
  const float* W1   = (const float*)d_in[3];
  const float* W2   = (const float*)d_in[4];
  const float* Ws1  = (const float*)d_in[5];
  const float* Ws2  = (const float*)d_in[6];
  float* out = (float*)d_out;

  char* p = (char*)d_ws;
  auto alloc = [&](size_t bytes) -> void* {
    void* r = (void*)p;
    p += (bytes + 255) & ~(size_t)255;
    return r;
  };
  int*   topk_idx   = (int*)  alloc((size_t)NSLOT * 4);
  float* topk_w     = (float*)alloc((size_t)NSLOT * 4);
  int*   counts     = (int*)  alloc(64);
  int*   offsets    = (int*)  alloc(64);
  int*   perm_token = (int*)  alloc((size_t)NSLOT * 4);
  float* perm_w     = (float*)alloc((size_t)NSLOT * 4);
  u16*   Xbf        = (u16*)  alloc((size_t)T_TOK * HDIM * 2);
  u16*   W1b        = (u16*)  alloc((size_t)NEXP * IDIM * HDIM * 2);
  u16*   W2b        = (u16*)  alloc((size_t)NEXP * HDIM * IDIM * 2);
  u16*   Ws1b       = (u16*)  alloc((size_t)ISDIM * HDIM * 2);
  u16*   Ws2b       = (u16*)  alloc((size_t)HDIM * ISDIM * 2);
  u16*   Hg         = (u16*)  alloc((size_t)NSLOT * IDIM * 2);
  u16*   Hs         = (u16*)  alloc((size_t)T_TOK * ISDIM * 2);

  router_kernel<<<T_TOK, 256, 0, stream>>>(x, Wg, bias, topk_idx, topk_w, Xbf);
  route_build<<<1, 256, 0, stream>>>(topk_idx, topk_w, offsets, counts,
                                     perm_token, perm_w);

  {
    int n4 = NEXP * IDIM * HDIM / 4;
    cvt_kernel<<<(n4 + 255) / 256, 256, 0, stream>>>(W1, W1b, n4);
    cvt_kernel<<<(n4 + 255) / 256, 256, 0, stream>>>(W2, W2b, n4);
    int n4s = ISDIM * HDIM / 4;
    cvt_kernel<<<(n4s + 255) / 256, 256, 0, stream>>>(Ws1, Ws1b, n4s);
    cvt_kernel<<<(n4s + 255) / 256, 256, 0, stream>>>(Ws2, Ws2b, n4s);
  }

  // routed up: Hg[slot, I] = perm_w * relu2(x[tok] @ W1[e]^T)
  gemm_nt<0><<<dim3(T_TOK / BM, IDIM / BN, NEXP), 256, 0, stream>>>(
      Xbf, W1b, HDIM, IDIM, offsets, counts, 0, (size_t)IDIM * HDIM,
      perm_token, Hg, nullptr, perm_w, nullptr);

  // shared up: Hs = relu2(x @ Ws1^T)
  gemm_nt<1><<<dim3(T_TOK / BM, ISDIM / BN, 1), 256, 0, stream>>>(
      Xbf, Ws1b, HDIM, ISDIM, nullptr, nullptr, T_TOK, 0,
      nullptr, Hs, nullptr, nullptr, nullptr);

  // shared down: out = Hs @ Ws2^T  (full fp32 store, runs before routed atomics)
  gemm_nt<2><<<dim3(T_TOK / BM, HDIM / BN, 1), 256, 0, stream>>>(
      Hs, Ws2b, ISDIM, HDIM, nullptr, nullptr, T_TOK, 0,
      nullptr, nullptr, out, nullptr, nullptr);

  // routed down: out[tok] += Hg[slot] @ W2[e]^T  (fp32 atomics)
  gemm_nt<3><<<dim3(T_TOK / BM, HDIM / BN, NEXP), 256, 0, stream>>>(
      Hg, W2b, IDIM, HDIM, offsets, counts, 0, (size_t)HDIM * IDIM,
      nullptr, nullptr, out, nullptr, perm_token);
}

// Round 4
// 340.842 us; speedup vs baseline: 1.3839x; 1.0818x over previous
//
#include <hip/hip_runtime.h>
#include <hip/hip_bf16.h>

#define T_TOK 2048
#define HDIM 1024
#define IDIM 512
#define ISDIM 1024
#define NEXP 16
#define TOPK 4
#define NSLOT (T_TOK*TOPK)
#define SCALE_F 2.5f

typedef unsigned short u16;
typedef float f32x4 __attribute__((ext_vector_type(4)));
typedef __bf16 bf16x8 __attribute__((ext_vector_type(8)));
typedef u16 u16x8 __attribute__((ext_vector_type(8)));

__device__ __forceinline__ u16 f2bf(float f) {
  unsigned u = __builtin_bit_cast(unsigned, f);
  u += 0x7fffu + ((u >> 16) & 1u);   // round-to-nearest-even
  return (u16)(u >> 16);
}

__device__ __forceinline__ void gload_lds16(const u16* g, u16* l) {
  // async global->LDS, 16B/lane; data lands at (wave-uniform l) + lane*16
  __builtin_amdgcn_global_load_lds(
      (const __attribute__((address_space(1))) void*)g,
      (__attribute__((address_space(3))) void*)l, 16, 0, 0);
}

__device__ __forceinline__ f32x4 mfma16(u16x8 a, u16x8 b, f32x4 c) {
  return __builtin_amdgcn_mfma_f32_16x16x32_bf16(
      __builtin_bit_cast(bf16x8, a), __builtin_bit_cast(bf16x8, b), c, 0, 0, 0);
}

// ---------------- router: 256 threads/token, float4 dots, no atomics ------
__global__ void __launch_bounds__(256) router_kernel(
    const float* __restrict__ x, const float* __restrict__ Wg,
    const float* __restrict__ bias,
    int* __restrict__ topk_idx, float* __restrict__ topk_w,
    u16* __restrict__ Xbf) {
  int t = blockIdx.x;
  int tid = threadIdx.x;
  int lane = tid & 63;
  int wave = tid >> 6;

  __shared__ __align__(16) float sx[HDIM];
  __shared__ float ssc[NEXP];

  float4 xv = reinterpret_cast<const float4*>(x + (size_t)t * HDIM)[tid];
  reinterpret_cast<float4*>(sx)[tid] = xv;
  ushort4 o;
  o.x = f2bf(xv.x); o.y = f2bf(xv.y); o.z = f2bf(xv.z); o.w = f2bf(xv.w);
  reinterpret_cast<ushort4*>(Xbf + (size_t)t * HDIM)[tid] = o;
  __syncthreads();

  float acc[4] = {0.f, 0.f, 0.f, 0.f};
  const float4* sx4 = reinterpret_cast<const float4*>(sx);
#pragma unroll
  for (int c = 0; c < 4; c++) {
    float4 xq = sx4[lane + 64 * c];
#pragma unroll
    for (int e = 0; e < 4; e++) {
      float4 wq = reinterpret_cast<const float4*>(
          Wg + (size_t)(wave * 4 + e) * HDIM)[lane + 64 * c];
      acc[e] += xq.x * wq.x + xq.y * wq.y + xq.z * wq.z + xq.w * wq.w;
    }
  }
#pragma unroll
  for (int e = 0; e < 4; e++) {
    float v = acc[e];
#pragma unroll
    for (int off = 32; off > 0; off >>= 1) v += __shfl_xor(v, off);
    if (lane == 0) ssc[wave * 4 + e] = v;
  }
  __syncthreads();

  if (tid == 0) {
    float scores[NEXP], sc[NEXP];
#pragma unroll
    for (int e = 0; e < NEXP; e++) {
      float s = 1.f / (1.f + expf(-ssc[e]));
      scores[e] = s;
      sc[e] = s + bias[e];
    }
    float gsum[4];
#pragma unroll
    for (int g = 0; g < 4; g++) {
      float a = sc[4*g], b = sc[4*g+1], c = sc[4*g+2], d = sc[4*g+3];
      float hi1 = fmaxf(a, b), lo1 = fminf(a, b);
      float hi2 = fmaxf(c, d), lo2 = fminf(c, d);
      gsum[g] = fmaxf(hi1, hi2) + fmaxf(fminf(hi1, hi2), fmaxf(lo1, lo2));
    }
    int g0 = 0; float bv = gsum[0];
#pragma unroll
    for (int g = 1; g < 4; g++) if (gsum[g] > bv) { bv = gsum[g]; g0 = g; }
    int g1 = -1; float bv2 = -1e30f;
#pragma unroll
    for (int g = 0; g < 4; g++) if (g != g0 && gsum[g] > bv2) { bv2 = gsum[g]; g1 = g; }
    float m[NEXP];
#pragma unroll
    for (int e = 0; e < NEXP; e++) {
      int g = e >> 2;
      m[e] = (g == g0 || g == g1) ? sc[e] : 0.0f;
    }
    int idx[TOPK]; float w[TOPK];
#pragma unroll
    for (int k = 0; k < TOPK; k++) {
      int bj = 0; float bmv = m[0];
#pragma unroll
      for (int j = 1; j < NEXP; j++) if (m[j] > bmv) { bmv = m[j]; bj = j; }
      idx[k] = bj; w[k] = scores[bj];
#pragma unroll
      for (int j = 0; j < NEXP; j++) m[j] = (j == bj) ? -1e30f : m[j];
    }
    float s4 = w[0] + w[1] + w[2] + w[3] + 1e-20f;
    float inv = SCALE_F / s4;
#pragma unroll
    for (int k = 0; k < TOPK; k++) {
      topk_idx[t * TOPK + k] = idx[k];
      topk_w[t * TOPK + k] = w[k] * inv;
    }
  }
}

// ---------------- route_build: histogram + scan + scatter + inverse map ----
__global__ void __launch_bounds__(256) route_build(
    const int* __restrict__ topk_idx, const float* __restrict__ topk_w,
    int* __restrict__ offsets, int* __restrict__ counts,
    int* __restrict__ perm_token, float* __restrict__ perm_w,
    int* __restrict__ slot_of) {
  __shared__ int hcnt[NEXP];
  __shared__ int hfill[NEXP];
  int tid = threadIdx.x;
  if (tid < NEXP) hcnt[tid] = 0;
  __syncthreads();

  int e_loc[NSLOT / 256];
#pragma unroll
  for (int i = 0; i < NSLOT / 256; i++) {
    int j = tid + 256 * i;
    int e = topk_idx[j];
    e_loc[i] = e;
    atomicAdd(&hcnt[e], 1);
  }
  __syncthreads();

  if (tid == 0) {
    int s = 0;
#pragma unroll
    for (int e = 0; e < NEXP; e++) {
      int c = hcnt[e];
      offsets[e] = s;
      counts[e] = c;
      hfill[e] = s;
      s += c;
    }
  }
  __syncthreads();

#pragma unroll
  for (int i = 0; i < NSLOT / 256; i++) {
    int j = tid + 256 * i;
    int pos = atomicAdd(&hfill[e_loc[i]], 1);
    perm_token[pos] = j >> 2;
    perm_w[pos] = topk_w[j];
    slot_of[j] = pos;
  }
}

// ---------------- fp32 -> bf16 conversion ----------------
__global__ void cvt_kernel(const float* __restrict__ src, u16* __restrict__ dst, int n4) {
  int i = blockIdx.x * 256 + threadIdx.x;
  if (i >= n4) return;
  float4 v = reinterpret_cast<const float4*>(src)[i];
  ushort4 o;
  o.x = f2bf(v.x); o.y = f2bf(v.y); o.z = f2bf(v.z); o.w = f2bf(v.w);
  reinterpret_cast<ushort4*>(dst)[i] = o;
}

// ---------------- NT GEMM (m97 structure): 128x128 tile, BK=32, ----------
// global_load_lds width=16, 4x4 16x16x32 acc per wave.
// EPI 0: relu2 * rowscale -> bf16 at permuted rows  [routed up]
// EPI 1: relu2 -> bf16                              [shared up]
// EPI 2: fp32 store                                 [shared down]
// EPI 3: fp32 store to Yg at slot rows              [routed down, NO atomics]
#define BM 128
#define BN 128
#define BK 32

template<int EPI>
__global__ void __launch_bounds__(256) gemm_nt(
    const u16* __restrict__ A, const u16* __restrict__ B,
    int K, int N,
    const int* __restrict__ eoffs, const int* __restrict__ ecnts, int Mfull,
    size_t strideB,
    const int* __restrict__ rowmapA,
    u16* __restrict__ Cb, float* __restrict__ Cf,
    const float* __restrict__ rowscale)
{
  int e = blockIdx.z;
  int rowbase = eoffs ? eoffs[e] : 0;
  int Mloc = ecnts ? ecnts[e] : Mfull;
  int m0 = blockIdx.x * BM;
  if (m0 >= Mloc) return;
  int n0 = blockIdx.y * BN;
  const u16* Bp = B + (size_t)e * strideB;

  // unpadded: required by global_load_lds lane->base+lane*16 placement
  __shared__ __align__(16) u16 sA[BM * BK];
  __shared__ __align__(16) u16 sB[BN * BK];

  int tid = threadIdx.x;
  int lane = tid & 63;
  int wave = tid >> 6;
  int wm = (wave >> 1) * 64;
  int wn = (wave & 1) * 64;
  int fm = lane & 15;
  int kq = lane >> 4;          // 0..3

  // staging: wave w, chunk c covers tile rows [64c+16w, 64c+16w+16)
  // lane i -> row (i>>2), col (i&3)*8 ; LDS offset = lane*16B = row*64B+col*16B
  int lrow = lane >> 2;
  int lcol = (lane & 3) * 8;

  const u16* Ag[2];
  const u16* Bg[2];
  u16* sAw[2];
  u16* sBw[2];
#pragma unroll
  for (int c = 0; c < 2; c++) {
    int row = 64 * c + 16 * wave + lrow;
    int ar = m0 + row;
    int cl = (ar < Mloc) ? ar : (Mloc - 1);   // clamp OOB rows (stores masked)
    size_t asrc;
    if (rowmapA) asrc = (size_t)rowmapA[rowbase + cl] * K;
    else         asrc = (size_t)(rowbase + cl) * K;
    Ag[c] = A + asrc + lcol;
    Bg[c] = Bp + (size_t)(n0 + row) * K + lcol;
    sAw[c] = &sA[(64 * c + 16 * wave) * BK];
    sBw[c] = &sB[(64 * c + 16 * wave) * BK];
  }

  f32x4 acc[4][4] = {};

  for (int k0 = 0; k0 < K; k0 += BK) {
#pragma unroll
    for (int c = 0; c < 2; c++) {
      gload_lds16(Ag[c] + k0, sAw[c]);
      gload_lds16(Bg[c] + k0, sBw[c]);
    }
    __syncthreads();
    u16x8 af[4], bf[4];
#pragma unroll
    for (int i = 0; i < 4; i++) {
      af[i] = *reinterpret_cast<const u16x8*>(&sA[(wm + 16 * i + fm) * BK + kq * 8]);
      bf[i] = *reinterpret_cast<const u16x8*>(&sB[(wn + 16 * i + fm) * BK + kq * 8]);
    }
#pragma unroll
    for (int i = 0; i < 4; i++)
#pragma unroll
      for (int j = 0; j < 4; j++)
        acc[i][j] = mfma16(af[i], bf[j], acc[i][j]);
    __syncthreads();
  }

  // epilogue: C/D mapping col = lane&15, row = (lane>>4)*4 + reg (m89/m91)
#pragma unroll
  for (int i = 0; i < 4; i++) {
#pragma unroll
    for (int j = 0; j < 4; j++) {
      int gn = n0 + wn + 16 * j + fm;
      f32x4 a = acc[i][j];
#pragma unroll
      for (int r = 0; r < 4; r++) {
        int gm = m0 + wm + 16 * i + kq * 4 + r;
        if (gm < Mloc) {
          float v = a[r];
          if (EPI == 0) {
            float tq = fmaxf(v, 0.f);
            tq = tq * tq * rowscale[rowbase + gm];
            Cb[(size_t)(rowbase + gm) * N + gn] = f2bf(tq);
          } else if (EPI == 1) {
            float tq = fmaxf(v, 0.f);
            Cb[(size_t)gm * N + gn] = f2bf(tq * tq);
          } else if (EPI == 2) {
            Cf[(size_t)gm * N + gn] = v;
          } else {
            Cf[(size_t)(rowbase + gm) * N + gn] = v;   // Yg plain store
          }
        }
      }
    }
  }
}

// ---------------- combine: out[t] += sum_k Yg[slot_of[t,k]] ----------------
__global__ void __launch_bounds__(256) combine_kernel(
    const float* __restrict__ Yg, const int* __restrict__ slot_of,
    float* __restrict__ out) {
  int t = blockIdx.x;
  int i = threadIdx.x;                       // 256 float4s = 1024 floats
  int4 s = *reinterpret_cast<const int4*>(&slot_of[t * 4]);
  const float4* Y4 = reinterpret_cast<const float4*>(Yg);
  float4* O4 = reinterpret_cast<float4*>(out);
  float4 v = O4[(size_t)t * 256 + i];        // shared-expert output already there
  float4 a = Y4[(size_t)s.x * 256 + i];
  float4 b = Y4[(size_t)s.y * 256 + i];
  float4 c = Y4[(size_t)s.z * 256 + i];
  float4 d = Y4[(size_t)s.w * 256 + i];
  v.x += a.x + b.x + c.x + d.x;
  v.y += a.y + b.y + c.y + d.y;
  v.z += a.z + b.z + c.z + d.z;
  v.w += a.w + b.w + c.w + d.w;
  O4[(size_t)t * 256 + i] = v;
}

// ---------------- launcher ----------------
extern "C" void kernel_launch(void* const* d_in, const int* in_sizes, int n_in,
                              void* d_out, int out_size, void* d_ws, size_t ws_size,
                              hipStream_t stream) {
  const float* x    = (const float*)d_in[0];
  const float* Wg   = (const float*)d_in[1];
  const float* bias = (const float*)d_in[2];
  const float* W1   = (const float*)d_in[3];
  const float* W2   = (const float*)d_in[4];
  const float* Ws1  = (const float*)d_in[5];
  const float* Ws2  = (const float*)d_in[6];
  float* out = (float*)d_out;

  char* p = (char*)d_ws;
  auto alloc = [&](size_t bytes) -> void* {
    void* r = (void*)p;
    p += (bytes + 255) & ~(size_t)255;
    return r;
  };
  int*   topk_idx   = (int*)  alloc((size_t)NSLOT * 4);
  float* topk_w     = (float*)alloc((size_t)NSLOT * 4);
  int*   counts     = (int*)  alloc(64);
  int*   offsets    = (int*)  alloc(64);
  int*   perm_token = (int*)  alloc((size_t)NSLOT * 4);
  float* perm_w     = (float*)alloc((size_t)NSLOT * 4);
  int*   slot_of    = (int*)  alloc((size_t)NSLOT * 4);
  u16*   Xbf        = (u16*)  alloc((size_t)T_TOK * HDIM * 2);
  u16*   W1b        = (u16*)  alloc((size_t)NEXP * IDIM * HDIM * 2);
  u16*   W2b        = (u16*)  alloc((size_t)NEXP * HDIM * IDIM * 2);
  u16*   Ws1b       = (u16*)  alloc((size_t)ISDIM * HDIM * 2);
  u16*   Ws2b       = (u16*)  alloc((size_t)HDIM * ISDIM * 2);
  u16*   Hg         = (u16*)  alloc((size_t)NSLOT * IDIM * 2);
  u16*   Hs         = (u16*)  alloc((size_t)T_TOK * ISDIM * 2);
  float* Yg         = (float*)alloc((size_t)NSLOT * HDIM * 4);

  router_kernel<<<T_TOK, 256, 0, stream>>>(x, Wg, bias, topk_idx, topk_w, Xbf);
  route_build<<<1, 256, 0, stream>>>(topk_idx, topk_w, offsets, counts,
                                     perm_token, perm_w, slot_of);

  {
    int n4 = NEXP * IDIM * HDIM / 4;
    cvt_kernel<<<(n4 + 255) / 256, 256, 0, stream>>>(W1, W1b, n4);
    cvt_kernel<<<(n4 + 255) / 256, 256, 0, stream>>>(W2, W2b, n4);
    int n4s = ISDIM * HDIM / 4;
    cvt_kernel<<<(n4s + 255) / 256, 256, 0, stream>>>(Ws1, Ws1b, n4s);
    cvt_kernel<<<(n4s + 255) / 256, 256, 0, stream>>>(Ws2, Ws2b, n4s);
  }

  // routed up: Hg[slot, I] = perm_w * relu2(x[tok] @ W1[e]^T)
  gemm_nt<0><<<dim3(T_TOK / BM, IDIM / BN, NEXP), 256, 0, stream>>>(
      Xbf, W1b, HDIM, IDIM, offsets, counts, 0, (size_t)IDIM * HDIM,
      perm_token, Hg, nullptr, perm_w);

  // shared up: Hs = relu2(x @ Ws1^T)
  gemm_nt<1><<<dim3(T_TOK / BM, ISDIM / BN, 1), 256, 0, stream>>>(
      Xbf, Ws1b, HDIM, ISDIM, nullptr, nullptr, T_TOK, 0,
      nullptr, Hs, nullptr, nullptr);

  // shared down: out = Hs @ Ws2^T  (fp32 store)
  gemm_nt<2><<<dim3(T_TOK / BM, HDIM / BN, 1), 256, 0, stream>>>(
      Hs, Ws2b, ISDIM, HDIM, nullptr, nullptr, T_TOK, 0,
      nullptr, nullptr, out, nullptr);

  // routed down: Yg[slot] = Hg[slot] @ W2[e]^T  (plain fp32 store)
  gemm_nt<3><<<dim3(T_TOK / BM, HDIM / BN, NEXP), 256, 0, stream>>>(
      Hg, W2b, IDIM, HDIM, offsets, counts, 0, (size_t)HDIM * IDIM,
      nullptr, nullptr, Yg, nullptr);

  // gather-combine: out[t] += sum_k Yg[slot_of[t,k]]
  combine_kernel<<<T_TOK, 256, 0, stream>>>(Yg, slot_of, out);
}

// Round 5
// 306.894 us; speedup vs baseline: 1.5370x; 1.1106x over previous
//
#include <hip/hip_runtime.h>
#include <hip/hip_bf16.h>

#define T_TOK 2048
#define HDIM 1024
#define IDIM 512
#define ISDIM 1024
#define NEXP 16
#define TOPK 4
#define NSLOT (T_TOK*TOPK)
#define SCALE_F 2.5f

typedef unsigned short u16;
typedef float f32x4 __attribute__((ext_vector_type(4)));
typedef __bf16 bf16x8 __attribute__((ext_vector_type(8)));
typedef u16 u16x8 __attribute__((ext_vector_type(8)));

__device__ __forceinline__ u16 f2bf(float f) {
  unsigned u = __builtin_bit_cast(unsigned, f);
  u += 0x7fffu + ((u >> 16) & 1u);   // round-to-nearest-even
  return (u16)(u >> 16);
}

__device__ __forceinline__ void gload_lds16(const u16* g, u16* l) {
  // async global->LDS, 16B/lane; data lands at (wave-uniform l) + lane*16
  __builtin_amdgcn_global_load_lds(
      (const __attribute__((address_space(1))) void*)g,
      (__attribute__((address_space(3))) void*)l, 16, 0, 0);
}

__device__ __forceinline__ f32x4 mfma16(u16x8 a, u16x8 b, f32x4 c) {
  return __builtin_amdgcn_mfma_f32_16x16x32_bf16(
      __builtin_bit_cast(bf16x8, a), __builtin_bit_cast(bf16x8, b), c, 0, 0, 0);
}

// ---------------- router: 256 threads/token, float4 dots, no atomics ------
__global__ void __launch_bounds__(256) router_kernel(
    const float* __restrict__ x, const float* __restrict__ Wg,
    const float* __restrict__ bias,
    int* __restrict__ topk_idx, float* __restrict__ topk_w,
    u16* __restrict__ Xbf) {
  int t = blockIdx.x;
  int tid = threadIdx.x;
  int lane = tid & 63;
  int wave = tid >> 6;

  __shared__ __align__(16) float sx[HDIM];
  __shared__ float ssc[NEXP];

  float4 xv = reinterpret_cast<const float4*>(x + (size_t)t * HDIM)[tid];
  reinterpret_cast<float4*>(sx)[tid] = xv;
  ushort4 o;
  o.x = f2bf(xv.x); o.y = f2bf(xv.y); o.z = f2bf(xv.z); o.w = f2bf(xv.w);
  reinterpret_cast<ushort4*>(Xbf + (size_t)t * HDIM)[tid] = o;
  __syncthreads();

  float acc[4] = {0.f, 0.f, 0.f, 0.f};
  const float4* sx4 = reinterpret_cast<const float4*>(sx);
#pragma unroll
  for (int c = 0; c < 4; c++) {
    float4 xq = sx4[lane + 64 * c];
#pragma unroll
    for (int e = 0; e < 4; e++) {
      float4 wq = reinterpret_cast<const float4*>(
          Wg + (size_t)(wave * 4 + e) * HDIM)[lane + 64 * c];
      acc[e] += xq.x * wq.x + xq.y * wq.y + xq.z * wq.z + xq.w * wq.w;
    }
  }
#pragma unroll
  for (int e = 0; e < 4; e++) {
    float v = acc[e];
#pragma unroll
    for (int off = 32; off > 0; off >>= 1) v += __shfl_xor(v, off);
    if (lane == 0) ssc[wave * 4 + e] = v;
  }
  __syncthreads();

  if (tid == 0) {
    float scores[NEXP], sc[NEXP];
#pragma unroll
    for (int e = 0; e < NEXP; e++) {
      float s = 1.f / (1.f + expf(-ssc[e]));
      scores[e] = s;
      sc[e] = s + bias[e];
    }
    float gsum[4];
#pragma unroll
    for (int g = 0; g < 4; g++) {
      float a = sc[4*g], b = sc[4*g+1], c = sc[4*g+2], d = sc[4*g+3];
      float hi1 = fmaxf(a, b), lo1 = fminf(a, b);
      float hi2 = fmaxf(c, d), lo2 = fminf(c, d);
      gsum[g] = fmaxf(hi1, hi2) + fmaxf(fminf(hi1, hi2), fmaxf(lo1, lo2));
    }
    int g0 = 0; float bv = gsum[0];
#pragma unroll
    for (int g = 1; g < 4; g++) if (gsum[g] > bv) { bv = gsum[g]; g0 = g; }
    int g1 = -1; float bv2 = -1e30f;
#pragma unroll
    for (int g = 0; g < 4; g++) if (g != g0 && gsum[g] > bv2) { bv2 = gsum[g]; g1 = g; }
    float m[NEXP];
#pragma unroll
    for (int e = 0; e < NEXP; e++) {
      int g = e >> 2;
      m[e] = (g == g0 || g == g1) ? sc[e] : 0.0f;
    }
    int idx[TOPK]; float w[TOPK];
#pragma unroll
    for (int k = 0; k < TOPK; k++) {
      int bj = 0; float bmv = m[0];
#pragma unroll
      for (int j = 1; j < NEXP; j++) if (m[j] > bmv) { bmv = m[j]; bj = j; }
      idx[k] = bj; w[k] = scores[bj];
#pragma unroll
      for (int j = 0; j < NEXP; j++) m[j] = (j == bj) ? -1e30f : m[j];
    }
    float s4 = w[0] + w[1] + w[2] + w[3] + 1e-20f;
    float inv = SCALE_F / s4;
#pragma unroll
    for (int k = 0; k < TOPK; k++) {
      topk_idx[t * TOPK + k] = idx[k];
      topk_w[t * TOPK + k] = w[k] * inv;
    }
  }
}

// ---------------- route_build: histogram + scan + scatter + inverse map ----
__global__ void __launch_bounds__(256) route_build(
    const int* __restrict__ topk_idx, const float* __restrict__ topk_w,
    int* __restrict__ offsets, int* __restrict__ counts,
    int* __restrict__ perm_token, float* __restrict__ perm_w,
    int* __restrict__ slot_of) {
  __shared__ int hcnt[NEXP];
  __shared__ int hfill[NEXP];
  int tid = threadIdx.x;
  if (tid < NEXP) hcnt[tid] = 0;
  __syncthreads();

  int e_loc[NSLOT / 256];
#pragma unroll
  for (int i = 0; i < NSLOT / 256; i++) {
    int j = tid + 256 * i;
    int e = topk_idx[j];
    e_loc[i] = e;
    atomicAdd(&hcnt[e], 1);
  }
  __syncthreads();

  if (tid == 0) {
    int s = 0;
#pragma unroll
    for (int e = 0; e < NEXP; e++) {
      int c = hcnt[e];
      offsets[e] = s;
      counts[e] = c;
      hfill[e] = s;
      s += c;
    }
  }
  __syncthreads();

#pragma unroll
  for (int i = 0; i < NSLOT / 256; i++) {
    int j = tid + 256 * i;
    int pos = atomicAdd(&hfill[e_loc[i]], 1);
    perm_token[pos] = j >> 2;
    perm_w[pos] = topk_w[j];
    slot_of[j] = pos;
  }
}

// ---------------- fp32 -> bf16 conversion ----------------
__global__ void cvt_kernel(const float* __restrict__ src, u16* __restrict__ dst, int n4) {
  int i = blockIdx.x * 256 + threadIdx.x;
  if (i >= n4) return;
  float4 v = reinterpret_cast<const float4*>(src)[i];
  ushort4 o;
  o.x = f2bf(v.x); o.y = f2bf(v.y); o.z = f2bf(v.z); o.w = f2bf(v.w);
  reinterpret_cast<ushort4*>(dst)[i] = o;
}

// ---------------- fused MoE GEMM: 64x128 tile, BK=32, gload_lds width=16 --
// R4: 128x128 tiles gave only ~256 active blocks -> 1 block/CU, occupancy
// 6.5%, MfmaUtil 4.6% (latency-bound at the barrier drain). Fix: smaller
// tiles + fuse routed(z<16) and shared(z=16) into one launch per phase.
// PHASE 0: up-proj.   z<16: Hg[slot]=w*relu2(x[tok] @ W1[e]^T)  (bf16)
//                     z=16: Hs = relu2(x @ Ws1^T)               (bf16)
// PHASE 1: down-proj. z<16: Yg[slot] = Hg[slot] @ W2[e]^T       (fp32)
//                     z=16: out = Hs @ Ws2^T                    (fp32)
#define BM 64
#define BN 128
#define BK 32

template<int PHASE>
__global__ void __launch_bounds__(256) moe_gemm(
    const u16* __restrict__ Xbf, const u16* __restrict__ Hg,
    const u16* __restrict__ Hs,
    const u16* __restrict__ W1b, const u16* __restrict__ W2b,
    const u16* __restrict__ Ws1b, const u16* __restrict__ Ws2b,
    const int* __restrict__ eoffs, const int* __restrict__ ecnts,
    const int* __restrict__ rowmap, const float* __restrict__ rowscale,
    u16* __restrict__ HgOut, u16* __restrict__ HsOut,
    float* __restrict__ Yg, float* __restrict__ outp)
{
  int e = blockIdx.z;
  bool sh = (e == NEXP);
  int K, N, Mloc, rowbase;
  const u16* Abase;
  const u16* Bp;
  if (PHASE == 0) {
    K = HDIM;
    if (sh) { N = ISDIM; Mloc = T_TOK; rowbase = 0; Abase = Xbf; Bp = Ws1b; }
    else    { N = IDIM; Mloc = ecnts[e]; rowbase = eoffs[e]; Abase = Xbf;
              Bp = W1b + (size_t)e * IDIM * HDIM; }
  } else {
    N = HDIM;
    if (sh) { K = ISDIM; Mloc = T_TOK; rowbase = 0; Abase = Hs; Bp = Ws2b; }
    else    { K = IDIM; Mloc = ecnts[e]; rowbase = eoffs[e]; Abase = Hg;
              Bp = W2b + (size_t)e * HDIM * IDIM; }
  }
  int m0 = blockIdx.x * BM;
  if (m0 >= Mloc) return;
  int n0 = blockIdx.y * BN;
  if (n0 >= N) return;

  // unpadded: required by global_load_lds lane->base+lane*16 placement
  __shared__ __align__(16) u16 sA[BM * BK];
  __shared__ __align__(16) u16 sB[BN * BK];

  int tid = threadIdx.x;
  int lane = tid & 63;
  int wave = tid >> 6;
  int wm = (wave >> 1) * 32;   // wave covers 32x64 of the 64x128 tile
  int wn = (wave & 1) * 64;
  int fm = lane & 15;
  int kq = lane >> 4;          // 0..3

  // staging: lane i -> row (i>>2), col (i&3)*8 ; LDS dest = base + lane*16B
  int lrow = lane >> 2;
  int lcol = (lane & 3) * 8;

  // A: wave w stages tile rows [16w,16w+16) with 1 gload
  int ar = m0 + 16 * wave + lrow;
  int arc = (ar < Mloc) ? ar : (Mloc - 1);          // clamp; stores masked
  size_t asrc;
  if (PHASE == 0 && !sh) asrc = (size_t)rowmap[rowbase + arc] * K;
  else                   asrc = (size_t)((sh ? 0 : rowbase) + arc) * K;
  const u16* Ag = Abase + asrc + lcol;
  u16* sAw = &sA[(16 * wave) * BK];
  // B: wave w stages tile rows [32w,32w+32) with 2 gloads
  const u16* Bg0 = Bp + (size_t)(n0 + 32 * wave + lrow) * K + lcol;
  const u16* Bg1 = Bg0 + (size_t)16 * K;
  u16* sBw0 = &sB[(32 * wave) * BK];
  u16* sBw1 = &sB[(32 * wave + 16) * BK];

  f32x4 acc[2][4] = {};

  for (int k0 = 0; k0 < K; k0 += BK) {
    gload_lds16(Ag + k0, sAw);
    gload_lds16(Bg0 + k0, sBw0);
    gload_lds16(Bg1 + k0, sBw1);
    __syncthreads();
    u16x8 af[2], bf[4];
#pragma unroll
    for (int i = 0; i < 2; i++)
      af[i] = *reinterpret_cast<const u16x8*>(&sA[(wm + 16 * i + fm) * BK + kq * 8]);
#pragma unroll
    for (int j = 0; j < 4; j++)
      bf[j] = *reinterpret_cast<const u16x8*>(&sB[(wn + 16 * j + fm) * BK + kq * 8]);
#pragma unroll
    for (int i = 0; i < 2; i++)
#pragma unroll
      for (int j = 0; j < 4; j++)
        acc[i][j] = mfma16(af[i], bf[j], acc[i][j]);
    __syncthreads();
  }

  // epilogue: C/D mapping col = lane&15, row = (lane>>4)*4 + reg (m89/m91)
#pragma unroll
  for (int i = 0; i < 2; i++) {
#pragma unroll
    for (int j = 0; j < 4; j++) {
      int gn = n0 + wn + 16 * j + fm;
      f32x4 a = acc[i][j];
#pragma unroll
      for (int r = 0; r < 4; r++) {
        int gm = m0 + wm + 16 * i + kq * 4 + r;
        if (gm < Mloc) {
          float v = a[r];
          if (PHASE == 0) {
            float tq = fmaxf(v, 0.f);
            if (!sh) {
              tq = tq * tq * rowscale[rowbase + gm];
              HgOut[(size_t)(rowbase + gm) * IDIM + gn] = f2bf(tq);
            } else {
              HsOut[(size_t)gm * ISDIM + gn] = f2bf(tq * tq);
            }
          } else {
            if (!sh) Yg[(size_t)(rowbase + gm) * HDIM + gn] = v;
            else     outp[(size_t)gm * HDIM + gn] = v;
          }
        }
      }
    }
  }
}

// ---------------- combine: out[t] += sum_k Yg[slot_of[t,k]] ----------------
__global__ void __launch_bounds__(256) combine_kernel(
    const float* __restrict__ Yg, const int* __restrict__ slot_of,
    float* __restrict__ out) {
  int t = blockIdx.x;
  int i = threadIdx.x;                       // 256 float4s = 1024 floats
  int4 s = *reinterpret_cast<const int4*>(&slot_of[t * 4]);
  const float4* Y4 = reinterpret_cast<const float4*>(Yg);
  float4* O4 = reinterpret_cast<float4*>(out);
  float4 v = O4[(size_t)t * 256 + i];        // shared-expert output already there
  float4 a = Y4[(size_t)s.x * 256 + i];
  float4 b = Y4[(size_t)s.y * 256 + i];
  float4 c = Y4[(size_t)s.z * 256 + i];
  float4 d = Y4[(size_t)s.w * 256 + i];
  v.x += a.x + b.x + c.x + d.x;
  v.y += a.y + b.y + c.y + d.y;
  v.z += a.z + b.z + c.z + d.z;
  v.w += a.w + b.w + c.w + d.w;
  O4[(size_t)t * 256 + i] = v;
}

// ---------------- launcher ----------------
extern "C" void kernel_launch(void* const* d_in, const int* in_sizes, int n_in,
                              void* d_out, int out_size, void* d_ws, size_t ws_size,
                              hipStream_t stream) {
  const float* x    = (const float*)d_in[0];
  const float* Wg   = (const float*)d_in[1];
  const float* bias = (const float*)d_in[2];
  const float* W1   = (const float*)d_in[3];
  const float* W2   = (const float*)d_in[4];
  const float* Ws1  = (const float*)d_in[5];
  const float* Ws2  = (const float*)d_in[6];
  float* out = (float*)d_out;

  char* p = (char*)d_ws;
  auto alloc = [&](size_t bytes) -> void* {
    void* r = (void*)p;
    p += (bytes + 255) & ~(size_t)255;
    return r;
  };
  int*   topk_idx   = (int*)  alloc((size_t)NSLOT * 4);
  float* topk_w     = (float*)alloc((size_t)NSLOT * 4);
  int*   counts     = (int*)  alloc(64);
  int*   offsets    = (int*)  alloc(64);
  int*   perm_token = (int*)  alloc((size_t)NSLOT * 4);
  float* perm_w     = (float*)alloc((size_t)NSLOT * 4);
  int*   slot_of    = (int*)  alloc((size_t)NSLOT * 4);
  u16*   Xbf        = (u16*)  alloc((size_t)T_TOK * HDIM * 2);
  u16*   W1b        = (u16*)  alloc((size_t)NEXP * IDIM * HDIM * 2);
  u16*   W2b        = (u16*)  alloc((size_t)NEXP * HDIM * IDIM * 2);
  u16*   Ws1b      = (u16*)  alloc((size_t)ISDIM * HDIM * 2);
  u16*   Ws2b      = (u16*)  alloc((size_t)HDIM * ISDIM * 2);
  u16*   Hg         = (u16*)  alloc((size_t)NSLOT * IDIM * 2);
  u16*   Hs         = (u16*)  alloc((size_t)T_TOK * ISDIM * 2);
  float* Yg         = (float*)alloc((size_t)NSLOT * HDIM * 4);

  router_kernel<<<T_TOK, 256, 0, stream>>>(x, Wg, bias, topk_idx, topk_w, Xbf);
  route_build<<<1, 256, 0, stream>>>(topk_idx, topk_w, offsets, counts,
                                     perm_token, perm_w, slot_of);

  {
    int n4 = NEXP * IDIM * HDIM / 4;
    cvt_kernel<<<(n4 + 255) / 256, 256, 0, stream>>>(W1, W1b, n4);
    cvt_kernel<<<(n4 + 255) / 256, 256, 0, stream>>>(W2, W2b, n4);
    int n4s = ISDIM * HDIM / 4;
    cvt_kernel<<<(n4s + 255) / 256, 256, 0, stream>>>(Ws1, Ws1b, n4s);
    cvt_kernel<<<(n4s + 255) / 256, 256, 0, stream>>>(Ws2, Ws2b, n4s);
  }

  // phase A: routed up (z<16) + shared up (z=16), one launch
  moe_gemm<0><<<dim3(T_TOK / BM, ISDIM / BN, NEXP + 1), 256, 0, stream>>>(
      Xbf, Hg, Hs, W1b, W2b, Ws1b, Ws2b, offsets, counts,
      perm_token, perm_w, Hg, Hs, nullptr, nullptr);

  // phase B: routed down (z<16) + shared down (z=16), one launch
  moe_gemm<1><<<dim3(T_TOK / BM, HDIM / BN, NEXP + 1), 256, 0, stream>>>(
      Xbf, Hg, Hs, W1b, W2b, Ws1b, Ws2b, offsets, counts,
      perm_token, perm_w, Hg, Hs, Yg, out);

  // gather-combine: out[t] += sum_k Yg[slot_of[t,k]]
  combine_kernel<<<T_TOK, 256, 0, stream>>>(Yg, slot_of, out);
}

// Round 6
// 279.384 us; speedup vs baseline: 1.6883x; 1.0985x over previous
//
#include <hip/hip_runtime.h>
#include <hip/hip_bf16.h>

#define T_TOK 2048
#define HDIM 1024
#define IDIM 512
#define ISDIM 1024
#define NEXP 16
#define TOPK 4
#define NSLOT (T_TOK*TOPK)
#define SCALE_F 2.5f

typedef unsigned short u16;
typedef float f32x4 __attribute__((ext_vector_type(4)));
typedef __bf16 bf16x8 __attribute__((ext_vector_type(8)));
typedef u16 u16x8 __attribute__((ext_vector_type(8)));

__device__ __forceinline__ u16 f2bf(float f) {
  unsigned u = __builtin_bit_cast(unsigned, f);
  u += 0x7fffu + ((u >> 16) & 1u);   // round-to-nearest-even
  return (u16)(u >> 16);
}

__device__ __forceinline__ void gload_lds16(const u16* g, u16* l) {
  // async global->LDS, 16B/lane; data lands at (wave-uniform l) + lane*16
  __builtin_amdgcn_global_load_lds(
      (const __attribute__((address_space(1))) void*)g,
      (__attribute__((address_space(3))) void*)l, 16, 0, 0);
}

__device__ __forceinline__ f32x4 mfma16(u16x8 a, u16x8 b, f32x4 c) {
  return __builtin_amdgcn_mfma_f32_16x16x32_bf16(
      __builtin_bit_cast(bf16x8, a), __builtin_bit_cast(bf16x8, b), c, 0, 0, 0);
}

// ---------------- router: 256 threads/token, float4 dots, no atomics ------
__global__ void __launch_bounds__(256) router_kernel(
    const float* __restrict__ x, const float* __restrict__ Wg,
    const float* __restrict__ bias,
    int* __restrict__ topk_idx, float* __restrict__ topk_w,
    u16* __restrict__ Xbf) {
  int t = blockIdx.x;
  int tid = threadIdx.x;
  int lane = tid & 63;
  int wave = tid >> 6;

  __shared__ __align__(16) float sx[HDIM];
  __shared__ float ssc[NEXP];

  float4 xv = reinterpret_cast<const float4*>(x + (size_t)t * HDIM)[tid];
  reinterpret_cast<float4*>(sx)[tid] = xv;
  ushort4 o;
  o.x = f2bf(xv.x); o.y = f2bf(xv.y); o.z = f2bf(xv.z); o.w = f2bf(xv.w);
  reinterpret_cast<ushort4*>(Xbf + (size_t)t * HDIM)[tid] = o;
  __syncthreads();

  float acc[4] = {0.f, 0.f, 0.f, 0.f};
  const float4* sx4 = reinterpret_cast<const float4*>(sx);
#pragma unroll
  for (int c = 0; c < 4; c++) {
    float4 xq = sx4[lane + 64 * c];
#pragma unroll
    for (int e = 0; e < 4; e++) {
      float4 wq = reinterpret_cast<const float4*>(
          Wg + (size_t)(wave * 4 + e) * HDIM)[lane + 64 * c];
      acc[e] += xq.x * wq.x + xq.y * wq.y + xq.z * wq.z + xq.w * wq.w;
    }
  }
#pragma unroll
  for (int e = 0; e < 4; e++) {
    float v = acc[e];
#pragma unroll
    for (int off = 32; off > 0; off >>= 1) v += __shfl_xor(v, off);
    if (lane == 0) ssc[wave * 4 + e] = v;
  }
  __syncthreads();

  if (tid == 0) {
    float scores[NEXP], sc[NEXP];
#pragma unroll
    for (int e = 0; e < NEXP; e++) {
      float s = 1.f / (1.f + expf(-ssc[e]));
      scores[e] = s;
      sc[e] = s + bias[e];
    }
    float gsum[4];
#pragma unroll
    for (int g = 0; g < 4; g++) {
      float a = sc[4*g], b = sc[4*g+1], c = sc[4*g+2], d = sc[4*g+3];
      float hi1 = fmaxf(a, b), lo1 = fminf(a, b);
      float hi2 = fmaxf(c, d), lo2 = fminf(c, d);
      gsum[g] = fmaxf(hi1, hi2) + fmaxf(fminf(hi1, hi2), fmaxf(lo1, lo2));
    }
    int g0 = 0; float bv = gsum[0];
#pragma unroll
    for (int g = 1; g < 4; g++) if (gsum[g] > bv) { bv = gsum[g]; g0 = g; }
    int g1 = -1; float bv2 = -1e30f;
#pragma unroll
    for (int g = 0; g < 4; g++) if (g != g0 && gsum[g] > bv2) { bv2 = gsum[g]; g1 = g; }
    float m[NEXP];
#pragma unroll
    for (int e = 0; e < NEXP; e++) {
      int g = e >> 2;
      m[e] = (g == g0 || g == g1) ? sc[e] : 0.0f;
    }
    int idx[TOPK]; float w[TOPK];
#pragma unroll
    for (int k = 0; k < TOPK; k++) {
      int bj = 0; float bmv = m[0];
#pragma unroll
      for (int j = 1; j < NEXP; j++) if (m[j] > bmv) { bmv = m[j]; bj = j; }
      idx[k] = bj; w[k] = scores[bj];
#pragma unroll
      for (int j = 0; j < NEXP; j++) m[j] = (j == bj) ? -1e30f : m[j];
    }
    float s4 = w[0] + w[1] + w[2] + w[3] + 1e-20f;
    float inv = SCALE_F / s4;
#pragma unroll
    for (int k = 0; k < TOPK; k++) {
      topk_idx[t * TOPK + k] = idx[k];
      topk_w[t * TOPK + k] = w[k] * inv;
    }
  }
}

// ---------------- route_build: histogram + scan + scatter + inverse map ----
__global__ void __launch_bounds__(256) route_build(
    const int* __restrict__ topk_idx, const float* __restrict__ topk_w,
    int* __restrict__ offsets, int* __restrict__ counts,
    int* __restrict__ perm_token, float* __restrict__ perm_w,
    int* __restrict__ slot_of) {
  __shared__ int hcnt[NEXP];
  __shared__ int hfill[NEXP];
  int tid = threadIdx.x;
  if (tid < NEXP) hcnt[tid] = 0;
  __syncthreads();

  int e_loc[NSLOT / 256];
#pragma unroll
  for (int i = 0; i < NSLOT / 256; i++) {
    int j = tid + 256 * i;
    int e = topk_idx[j];
    e_loc[i] = e;
    atomicAdd(&hcnt[e], 1);
  }
  __syncthreads();

  if (tid == 0) {
    int s = 0;
#pragma unroll
    for (int e = 0; e < NEXP; e++) {
      int c = hcnt[e];
      offsets[e] = s;
      counts[e] = c;
      hfill[e] = s;
      s += c;
    }
  }
  __syncthreads();

#pragma unroll
  for (int i = 0; i < NSLOT / 256; i++) {
    int j = tid + 256 * i;
    int pos = atomicAdd(&hfill[e_loc[i]], 1);
    perm_token[pos] = j >> 2;
    perm_w[pos] = topk_w[j];
    slot_of[j] = pos;
  }
}

// ---------------- fp32 -> bf16 conversion ----------------
__global__ void cvt_kernel(const float* __restrict__ src, u16* __restrict__ dst, int n4) {
  int i = blockIdx.x * 256 + threadIdx.x;
  if (i >= n4) return;
  float4 v = reinterpret_cast<const float4*>(src)[i];
  ushort4 o;
  o.x = f2bf(v.x); o.y = f2bf(v.y); o.z = f2bf(v.z); o.w = f2bf(v.w);
  reinterpret_cast<ushort4*>(dst)[i] = o;
}

// ---------------- fused MoE GEMM v3: 64x128 tile, BK=64, XOR-swizzle ------
// R5: BK=32 gave only 8 MFMA per barrier + 8-way LDS conflicts + K-imbalance
// (shared K=1024 vs routed K=512 tail). v3: BK=64 -> 16 MFMA/barrier;
// k-chunk XOR swizzle (applied on the GLOBAL side so global_load_lds's
// base+lane*16 layout is honored; 128B-line coalescing preserved) makes
// b128 LDS reads bank-uniform; shared expert split-K in phase 1 so every
// block runs exactly KL iterations.
// PHASE 0 (KL=1024): z<16: Hg[slot]=w*relu2(x[tok] @ W1[e]^T)   (bf16)
//                    z=16: Hs = relu2(x @ Ws1^T)                (bf16)
// PHASE 1 (KL=512):  z<16: Yg[slot] = Hg[slot] @ W2[e]^T        (fp32)
//                    z=16/17: Ys[half] = Hs[:,half] @ Ws2[:,half]^T (fp32)
#define BM 64
#define BN 128
#define BK 64

template<int PHASE>
__global__ void __launch_bounds__(256) moe_gemm(
    const u16* __restrict__ Xbf, const u16* __restrict__ Hg,
    const u16* __restrict__ Hs,
    const u16* __restrict__ W1b, const u16* __restrict__ W2b,
    const u16* __restrict__ Ws1b, const u16* __restrict__ Ws2b,
    const int* __restrict__ eoffs, const int* __restrict__ ecnts,
    const int* __restrict__ rowmap, const float* __restrict__ rowscale,
    u16* __restrict__ HgOut, u16* __restrict__ HsOut,
    float* __restrict__ Yg, float* __restrict__ Ys)
{
  constexpr int KL = (PHASE == 0) ? HDIM : IDIM;   // loop extent (uniform!)
  int e = blockIdx.z;
  bool sh = (e >= NEXP);
  int half = e - NEXP;                              // phase-1 shared K-half
  int N, Mloc, rowbase, Astr, Bstr, kb;
  const u16* Abase;
  const u16* Bp;
  if (PHASE == 0) {
    Astr = HDIM; Bstr = HDIM; kb = 0;
    if (sh) { N = ISDIM; Mloc = T_TOK; rowbase = 0; Abase = Xbf; Bp = Ws1b; }
    else    { N = IDIM; Mloc = ecnts[e]; rowbase = eoffs[e]; Abase = Xbf;
              Bp = W1b + (size_t)e * IDIM * HDIM; }
  } else {
    N = HDIM;
    if (sh) { Astr = ISDIM; Bstr = ISDIM; kb = half * IDIM;
              Mloc = T_TOK; rowbase = 0; Abase = Hs; Bp = Ws2b; }
    else    { Astr = IDIM; Bstr = IDIM; kb = 0;
              Mloc = ecnts[e]; rowbase = eoffs[e]; Abase = Hg;
              Bp = W2b + (size_t)e * HDIM * IDIM; }
  }
  int m0 = blockIdx.x * BM;
  if (m0 >= Mloc) return;
  int n0 = blockIdx.y * BN;
  if (n0 >= N) return;

  // unpadded: required by global_load_lds lane->base+lane*16 placement
  __shared__ __align__(16) u16 sA[BM * BK];   // 8 KB
  __shared__ __align__(16) u16 sB[BN * BK];   // 16 KB

  int tid = threadIdx.x;
  int lane = tid & 63;
  int wave = tid >> 6;
  int wm = (wave >> 1) * 32;   // wave computes 32x64 of the 64x128 tile
  int wn = (wave & 1) * 64;
  int fm = lane & 15;
  int kq = lane >> 4;          // 0..3
  int fsw = fm & 7;            // row&7 for fragment-row fm

  // staging: lane -> row (lane>>3), LDS chunk (lane&7); source chunk is
  // XOR-swizzled so LDS chunk l of row r holds global chunk l ^ (r&7)
  int lrow8 = lane >> 3;       // 0..7
  int sch = ((lane & 7) ^ lrow8) * 8;   // swizzled source k-offset (elems)

  // A: wave stages tile rows [16w,16w+16) via 2 gloads of 8 rows
  const u16* AgP[2];
  u16* sAw[2];
#pragma unroll
  for (int g = 0; g < 2; g++) {
    int rt = 16 * wave + 8 * g + lrow8;
    int ar = m0 + rt;
    int arc = (ar < Mloc) ? ar : (Mloc - 1);        // clamp; stores masked
    size_t asrc;
    if (PHASE == 0 && !sh) asrc = (size_t)rowmap[rowbase + arc] * Astr;
    else                   asrc = (size_t)((sh ? 0 : rowbase) + arc) * Astr;
    AgP[g] = Abase + asrc + kb + sch;
    sAw[g] = &sA[(16 * wave + 8 * g) * BK];
  }
  // B: wave stages tile rows [32w,32w+32) via 4 gloads of 8 rows
  const u16* BgP[4];
  u16* sBw[4];
#pragma unroll
  for (int g = 0; g < 4; g++) {
    int rt = 32 * wave + 8 * g + lrow8;
    BgP[g] = Bp + (size_t)(n0 + rt) * Bstr + kb + sch;
    sBw[g] = &sB[(32 * wave + 8 * g) * BK];
  }

  f32x4 acc[2][4] = {};

  for (int k0 = 0; k0 < KL; k0 += BK) {
#pragma unroll
    for (int g = 0; g < 2; g++) gload_lds16(AgP[g] + k0, sAw[g]);
#pragma unroll
    for (int g = 0; g < 4; g++) gload_lds16(BgP[g] + k0, sBw[g]);
    __syncthreads();
#pragma unroll
    for (int ks = 0; ks < 2; ks++) {
      int ch = ((ks * 4 + kq) ^ fsw) * 8;   // un-swizzle at read
      u16x8 af[2], bf[4];
#pragma unroll
      for (int i = 0; i < 2; i++)
        af[i] = *reinterpret_cast<const u16x8*>(&sA[(wm + 16 * i + fm) * BK + ch]);
#pragma unroll
      for (int j = 0; j < 4; j++)
        bf[j] = *reinterpret_cast<const u16x8*>(&sB[(wn + 16 * j + fm) * BK + ch]);
#pragma unroll
      for (int i = 0; i < 2; i++)
#pragma unroll
        for (int j = 0; j < 4; j++)
          acc[i][j] = mfma16(af[i], bf[j], acc[i][j]);
    }
    __syncthreads();
  }

  // epilogue: C/D mapping col = lane&15, row = (lane>>4)*4 + reg (m89/m91)
#pragma unroll
  for (int i = 0; i < 2; i++) {
#pragma unroll
    for (int j = 0; j < 4; j++) {
      int gn = n0 + wn + 16 * j + fm;
      f32x4 a = acc[i][j];
#pragma unroll
      for (int r = 0; r < 4; r++) {
        int gm = m0 + wm + 16 * i + kq * 4 + r;
        if (gm < Mloc) {
          float v = a[r];
          if (PHASE == 0) {
            float tq = fmaxf(v, 0.f);
            if (!sh) {
              tq = tq * tq * rowscale[rowbase + gm];
              HgOut[(size_t)(rowbase + gm) * IDIM + gn] = f2bf(tq);
            } else {
              HsOut[(size_t)gm * ISDIM + gn] = f2bf(tq * tq);
            }
          } else {
            if (!sh) Yg[(size_t)(rowbase + gm) * HDIM + gn] = v;
            else     Ys[(size_t)(half * T_TOK + gm) * HDIM + gn] = v;
          }
        }
      }
    }
  }
}

// ---- combine: out[t] = Ys0[t] + Ys1[t] + sum_k Yg[slot_of[t,k]] ----------
__global__ void __launch_bounds__(256) combine_kernel(
    const float* __restrict__ Yg, const float* __restrict__ Ys,
    const int* __restrict__ slot_of, float* __restrict__ out) {
  int t = blockIdx.x;
  int i = threadIdx.x;                       // 256 float4s = 1024 floats
  int4 s = *reinterpret_cast<const int4*>(&slot_of[t * 4]);
  const float4* Y4 = reinterpret_cast<const float4*>(Yg);
  const float4* S4 = reinterpret_cast<const float4*>(Ys);
  float4* O4 = reinterpret_cast<float4*>(out);
  float4 v0 = S4[(size_t)t * 256 + i];
  float4 v1 = S4[(size_t)(T_TOK + t) * 256 + i];
  float4 a = Y4[(size_t)s.x * 256 + i];
  float4 b = Y4[(size_t)s.y * 256 + i];
  float4 c = Y4[(size_t)s.z * 256 + i];
  float4 d = Y4[(size_t)s.w * 256 + i];
  float4 v;
  v.x = v0.x + v1.x + a.x + b.x + c.x + d.x;
  v.y = v0.y + v1.y + a.y + b.y + c.y + d.y;
  v.z = v0.z + v1.z + a.z + b.z + c.z + d.z;
  v.w = v0.w + v1.w + a.w + b.w + c.w + d.w;
  O4[(size_t)t * 256 + i] = v;
}

// ---------------- launcher ----------------
extern "C" void kernel_launch(void* const* d_in, const int* in_sizes, int n_in,
                              void* d_out, int out_size, void* d_ws, size_t ws_size,
                              hipStream_t stream) {
  const float* x    = (const float*)d_in[0];
  const float* Wg   = (const float*)d_in[1];
  const float* bias = (const float*)d_in[2];
  const float* W1   = (const float*)d_in[3];
  const float* W2   = (const float*)d_in[4];
  const float* Ws1  = (const float*)d_in[5];
  const float* Ws2  = (const float*)d_in[6];
  float* out = (float*)d_out;

  char* p = (char*)d_ws;
  auto alloc = [&](size_t bytes) -> void* {
    void* r = (void*)p;
    p += (bytes + 255) & ~(size_t)255;
    return r;
  };
  int*   topk_idx   = (int*)  alloc((size_t)NSLOT * 4);
  float* topk_w     = (float*)alloc((size_t)NSLOT * 4);
  int*   counts     = (int*)  alloc(64);
  int*   offsets    = (int*)  alloc(64);
  int*   perm_token = (int*)  alloc((size_t)NSLOT * 4);
  float* perm_w     = (float*)alloc((size_t)NSLOT * 4);
  int*   slot_of    = (int*)  alloc((size_t)NSLOT * 4);
  u16*   Xbf        = (u16*)  alloc((size_t)T_TOK * HDIM * 2);
  u16*   W1b        = (u16*)  alloc((size_t)NEXP * IDIM * HDIM * 2);
  u16*   W2b        = (u16*)  alloc((size_t)NEXP * HDIM * IDIM * 2);
  u16*   Ws1b      = (u16*)  alloc((size_t)ISDIM * HDIM * 2);
  u16*   Ws2b      = (u16*)  alloc((size_t)HDIM * ISDIM * 2);
  u16*   Hg         = (u16*)  alloc((size_t)NSLOT * IDIM * 2);
  u16*   Hs         = (u16*)  alloc((size_t)T_TOK * ISDIM * 2);
  float* Yg         = (float*)alloc((size_t)NSLOT * HDIM * 4);
  float* Ys         = (float*)alloc((size_t)2 * T_TOK * HDIM * 4);

  router_kernel<<<T_TOK, 256, 0, stream>>>(x, Wg, bias, topk_idx, topk_w, Xbf);
  route_build<<<1, 256, 0, stream>>>(topk_idx, topk_w, offsets, counts,
                                     perm_token, perm_w, slot_of);

  {
    int n4 = NEXP * IDIM * HDIM / 4;
    cvt_kernel<<<(n4 + 255) / 256, 256, 0, stream>>>(W1, W1b, n4);
    cvt_kernel<<<(n4 + 255) / 256, 256, 0, stream>>>(W2, W2b, n4);
    int n4s = ISDIM * HDIM / 4;
    cvt_kernel<<<(n4s + 255) / 256, 256, 0, stream>>>(Ws1, Ws1b, n4s);
    cvt_kernel<<<(n4s + 255) / 256, 256, 0, stream>>>(Ws2, Ws2b, n4s);
  }

  // phase A: routed up (z<16, N=512) + shared up (z=16), one launch
  moe_gemm<0><<<dim3(T_TOK / BM, ISDIM / BN, NEXP + 1), 256, 0, stream>>>(
      Xbf, Hg, Hs, W1b, W2b, Ws1b, Ws2b, offsets, counts,
      perm_token, perm_w, Hg, Hs, nullptr, nullptr);

  // phase B: routed down (z<16) + shared down split-K (z=16,17), one launch
  moe_gemm<1><<<dim3(T_TOK / BM, HDIM / BN, NEXP + 2), 256, 0, stream>>>(
      Xbf, Hg, Hs, W1b, W2b, Ws1b, Ws2b, offsets, counts,
      perm_token, perm_w, Hg, Hs, Yg, Ys);

  // combine: out[t] = Ys0 + Ys1 + sum_k Yg[slot_of[t,k]]
  combine_kernel<<<T_TOK, 256, 0, stream>>>(Yg, Ys, slot_of, out);
}

// Round 7
// 251.548 us; speedup vs baseline: 1.8752x; 1.1107x over previous
//
#include <hip/hip_runtime.h>
#include <hip/hip_bf16.h>

#define T_TOK 2048
#define HDIM 1024
#define IDIM 512
#define ISDIM 1024
#define NEXP 16
#define TOPK 4
#define NSLOT (T_TOK*TOPK)
#define SCALE_F 2.5f

typedef unsigned short u16;
typedef float f32x4 __attribute__((ext_vector_type(4)));
typedef __bf16 bf16x8 __attribute__((ext_vector_type(8)));
typedef u16 u16x8 __attribute__((ext_vector_type(8)));

__device__ __forceinline__ u16 f2bf(float f) {
  unsigned u = __builtin_bit_cast(unsigned, f);
  u += 0x7fffu + ((u >> 16) & 1u);   // round-to-nearest-even
  return (u16)(u >> 16);
}

__device__ __forceinline__ float bf2f(u16 h) {
  unsigned u = ((unsigned)h) << 16;
  return __builtin_bit_cast(float, u);
}

__device__ __forceinline__ void gload_lds16(const u16* g, u16* l) {
  // async global->LDS, 16B/lane; data lands at (wave-uniform l) + lane*16
  __builtin_amdgcn_global_load_lds(
      (const __attribute__((address_space(1))) void*)g,
      (__attribute__((address_space(3))) void*)l, 16, 0, 0);
}

__device__ __forceinline__ f32x4 mfma16(u16x8 a, u16x8 b, f32x4 c) {
  return __builtin_amdgcn_mfma_f32_16x16x32_bf16(
      __builtin_bit_cast(bf16x8, a), __builtin_bit_cast(bf16x8, b), c, 0, 0, 0);
}

// ---------------- router: 256 threads/token, float4 dots, no atomics ------
__global__ void __launch_bounds__(256) router_kernel(
    const float* __restrict__ x, const float* __restrict__ Wg,
    const float* __restrict__ bias,
    int* __restrict__ topk_idx, float* __restrict__ topk_w,
    u16* __restrict__ Xbf) {
  int t = blockIdx.x;
  int tid = threadIdx.x;
  int lane = tid & 63;
  int wave = tid >> 6;

  __shared__ __align__(16) float sx[HDIM];
  __shared__ float ssc[NEXP];

  float4 xv = reinterpret_cast<const float4*>(x + (size_t)t * HDIM)[tid];
  reinterpret_cast<float4*>(sx)[tid] = xv;
  ushort4 o;
  o.x = f2bf(xv.x); o.y = f2bf(xv.y); o.z = f2bf(xv.z); o.w = f2bf(xv.w);
  reinterpret_cast<ushort4*>(Xbf + (size_t)t * HDIM)[tid] = o;
  __syncthreads();

  float acc[4] = {0.f, 0.f, 0.f, 0.f};
  const float4* sx4 = reinterpret_cast<const float4*>(sx);
#pragma unroll
  for (int c = 0; c < 4; c++) {
    float4 xq = sx4[lane + 64 * c];
#pragma unroll
    for (int e = 0; e < 4; e++) {
      float4 wq = reinterpret_cast<const float4*>(
          Wg + (size_t)(wave * 4 + e) * HDIM)[lane + 64 * c];
      acc[e] += xq.x * wq.x + xq.y * wq.y + xq.z * wq.z + xq.w * wq.w;
    }
  }
#pragma unroll
  for (int e = 0; e < 4; e++) {
    float v = acc[e];
#pragma unroll
    for (int off = 32; off > 0; off >>= 1) v += __shfl_xor(v, off);
    if (lane == 0) ssc[wave * 4 + e] = v;
  }
  __syncthreads();

  if (tid == 0) {
    float scores[NEXP], sc[NEXP];
#pragma unroll
    for (int e = 0; e < NEXP; e++) {
      float s = 1.f / (1.f + expf(-ssc[e]));
      scores[e] = s;
      sc[e] = s + bias[e];
    }
    float gsum[4];
#pragma unroll
    for (int g = 0; g < 4; g++) {
      float a = sc[4*g], b = sc[4*g+1], c = sc[4*g+2], d = sc[4*g+3];
      float hi1 = fmaxf(a, b), lo1 = fminf(a, b);
      float hi2 = fmaxf(c, d), lo2 = fminf(c, d);
      gsum[g] = fmaxf(hi1, hi2) + fmaxf(fminf(hi1, hi2), fmaxf(lo1, lo2));
    }
    int g0 = 0; float bv = gsum[0];
#pragma unroll
    for (int g = 1; g < 4; g++) if (gsum[g] > bv) { bv = gsum[g]; g0 = g; }
    int g1 = -1; float bv2 = -1e30f;
#pragma unroll
    for (int g = 0; g < 4; g++) if (g != g0 && gsum[g] > bv2) { bv2 = gsum[g]; g1 = g; }
    float m[NEXP];
#pragma unroll
    for (int e = 0; e < NEXP; e++) {
      int g = e >> 2;
      m[e] = (g == g0 || g == g1) ? sc[e] : 0.0f;
    }
    int idx[TOPK]; float w[TOPK];
#pragma unroll
    for (int k = 0; k < TOPK; k++) {
      int bj = 0; float bmv = m[0];
#pragma unroll
      for (int j = 1; j < NEXP; j++) if (m[j] > bmv) { bmv = m[j]; bj = j; }
      idx[k] = bj; w[k] = scores[bj];
#pragma unroll
      for (int j = 0; j < NEXP; j++) m[j] = (j == bj) ? -1e30f : m[j];
    }
    float s4 = w[0] + w[1] + w[2] + w[3] + 1e-20f;
    float inv = SCALE_F / s4;
#pragma unroll
    for (int k = 0; k < TOPK; k++) {
      topk_idx[t * TOPK + k] = idx[k];
      topk_w[t * TOPK + k] = w[k] * inv;
    }
  }
}

// ---------------- route_build: histogram + scan + scatter + inverse map ----
__global__ void __launch_bounds__(256) route_build(
    const int* __restrict__ topk_idx, const float* __restrict__ topk_w,
    int* __restrict__ offsets, int* __restrict__ counts,
    int* __restrict__ perm_token, float* __restrict__ perm_w,
    int* __restrict__ slot_of) {
  __shared__ int hcnt[NEXP];
  __shared__ int hfill[NEXP];
  int tid = threadIdx.x;
  if (tid < NEXP) hcnt[tid] = 0;
  __syncthreads();

  int e_loc[NSLOT / 256];
#pragma unroll
  for (int i = 0; i < NSLOT / 256; i++) {
    int j = tid + 256 * i;
    int e = topk_idx[j];
    e_loc[i] = e;
    atomicAdd(&hcnt[e], 1);
  }
  __syncthreads();

  if (tid == 0) {
    int s = 0;
#pragma unroll
    for (int e = 0; e < NEXP; e++) {
      int c = hcnt[e];
      offsets[e] = s;
      counts[e] = c;
      hfill[e] = s;
      s += c;
    }
  }
  __syncthreads();

#pragma unroll
  for (int i = 0; i < NSLOT / 256; i++) {
    int j = tid + 256 * i;
    int pos = atomicAdd(&hfill[e_loc[i]], 1);
    perm_token[pos] = j >> 2;
    perm_w[pos] = topk_w[j];
    slot_of[j] = pos;
  }
}

// ---------------- single fused fp32 -> bf16 conversion over all weights ----
#define N1Q (NEXP*IDIM*HDIM/4)
#define NSQ (ISDIM*HDIM/4)
__global__ void __launch_bounds__(256) cvt_all(
    const float* __restrict__ W1, const float* __restrict__ W2,
    const float* __restrict__ Ws1, const float* __restrict__ Ws2,
    u16* __restrict__ W1b, u16* __restrict__ W2b,
    u16* __restrict__ Ws1b, u16* __restrict__ Ws2b) {
  int i = blockIdx.x * 256 + threadIdx.x;
  const float* src; u16* dst; int off;
  if (i < N1Q)               { src = W1;  dst = W1b;  off = i; }
  else if (i < 2 * N1Q)      { src = W2;  dst = W2b;  off = i - N1Q; }
  else if (i < 2 * N1Q + NSQ){ src = Ws1; dst = Ws1b; off = i - 2 * N1Q; }
  else                       { src = Ws2; dst = Ws2b; off = i - 2 * N1Q - NSQ; }
  float4 v = reinterpret_cast<const float4*>(src)[off];
  ushort4 o;
  o.x = f2bf(v.x); o.y = f2bf(v.y); o.z = f2bf(v.z); o.w = f2bf(v.w);
  reinterpret_cast<ushort4*>(dst)[off] = o;
}

// ---------------- fused MoE GEMM v4: 64x128, BK=64, XOR-swizzle, ----------
// XCD-locality remap. R6 showed FETCH=80MB vs ~40MB unique: the ~8
// m-blocks sharing one (e,n) B-tile were round-robined onto 8 different
// XCD L2s -> HBM-miss latency (~900cy) dominated at 3 blocks/CU.
// Remap: widx = (flat&7)*(total/8) + (flat>>3), m-fastest -> each XCD
// owns contiguous (e,n) groups; B-tile sharers colocate on one L2.
// PHASE 0 (KL=1024): e<16: Hg[slot]=w*relu2(x[tok] @ W1[e]^T)   (bf16)
//                    e=16: Hs = relu2(x @ Ws1^T)                (bf16)
// PHASE 1 (KL=512):  e<16: Ygb[slot] = Hg[slot] @ W2[e]^T       (bf16)
//                    e=16/17: Ys[half] = Hs[:,half] @ Ws2[:,half]^T (fp32)
#define BM 64
#define BN 128
#define BK 64

template<int PHASE>
__global__ void __launch_bounds__(256) moe_gemm(
    const u16* __restrict__ Xbf, const u16* __restrict__ Hg,
    const u16* __restrict__ Hs,
    const u16* __restrict__ W1b, const u16* __restrict__ W2b,
    const u16* __restrict__ Ws1b, const u16* __restrict__ Ws2b,
    const int* __restrict__ eoffs, const int* __restrict__ ecnts,
    const int* __restrict__ rowmap, const float* __restrict__ rowscale,
    u16* __restrict__ HgOut, u16* __restrict__ HsOut,
    u16* __restrict__ Ygb, float* __restrict__ Ys)
{
  constexpr int KL = (PHASE == 0) ? HDIM : IDIM;   // loop extent (uniform!)

  // XCD-locality work remap (dispatch: consecutive linear ids -> XCD id%8)
  int flat = blockIdx.x + gridDim.x * (blockIdx.y + gridDim.y * blockIdx.z);
  int chunk = (gridDim.x * gridDim.y * gridDim.z) >> 3;
  int widx = (flat & 7) * chunk + (flat >> 3);
  int mb = widx % gridDim.x;
  int tmp = widx / gridDim.x;
  int nb = tmp % gridDim.y;
  int e  = tmp / gridDim.y;

  bool sh = (e >= NEXP);
  int half = e - NEXP;                              // phase-1 shared K-half
  int N, Mloc, rowbase, Astr, Bstr, kb;
  const u16* Abase;
  const u16* Bp;
  if (PHASE == 0) {
    Astr = HDIM; Bstr = HDIM; kb = 0;
    if (sh) { N = ISDIM; Mloc = T_TOK; rowbase = 0; Abase = Xbf; Bp = Ws1b; }
    else    { N = IDIM; Mloc = ecnts[e]; rowbase = eoffs[e]; Abase = Xbf;
              Bp = W1b + (size_t)e * IDIM * HDIM; }
  } else {
    N = HDIM;
    if (sh) { Astr = ISDIM; Bstr = ISDIM; kb = half * IDIM;
              Mloc = T_TOK; rowbase = 0; Abase = Hs; Bp = Ws2b; }
    else    { Astr = IDIM; Bstr = IDIM; kb = 0;
              Mloc = ecnts[e]; rowbase = eoffs[e]; Abase = Hg;
              Bp = W2b + (size_t)e * HDIM * IDIM; }
  }
  int m0 = mb * BM;
  if (m0 >= Mloc) return;
  int n0 = nb * BN;
  if (n0 >= N) return;

  // unpadded: required by global_load_lds lane->base+lane*16 placement
  __shared__ __align__(16) u16 sA[BM * BK];   // 8 KB
  __shared__ __align__(16) u16 sB[BN * BK];   // 16 KB

  int tid = threadIdx.x;
  int lane = tid & 63;
  int wave = tid >> 6;
  int wm = (wave >> 1) * 32;   // wave computes 32x64 of the 64x128 tile
  int wn = (wave & 1) * 64;
  int fm = lane & 15;
  int kq = lane >> 4;          // 0..3
  int fsw = fm & 7;            // row&7 for fragment-row fm

  // staging: lane -> row (lane>>3), LDS chunk (lane&7); source chunk is
  // XOR-swizzled so LDS chunk l of row r holds global chunk l ^ (r&7)
  int lrow8 = lane >> 3;       // 0..7
  int sch = ((lane & 7) ^ lrow8) * 8;   // swizzled source k-offset (elems)

  // A: wave stages tile rows [16w,16w+16) via 2 gloads of 8 rows
  const u16* AgP[2];
  u16* sAw[2];
#pragma unroll
  for (int g = 0; g < 2; g++) {
    int rt = 16 * wave + 8 * g + lrow8;
    int ar = m0 + rt;
    int arc = (ar < Mloc) ? ar : (Mloc - 1);        // clamp; stores masked
    size_t asrc;
    if (PHASE == 0 && !sh) asrc = (size_t)rowmap[rowbase + arc] * Astr;
    else                   asrc = (size_t)((sh ? 0 : rowbase) + arc) * Astr;
    AgP[g] = Abase + asrc + kb + sch;
    sAw[g] = &sA[(16 * wave + 8 * g) * BK];
  }
  // B: wave stages tile rows [32w,32w+32) via 4 gloads of 8 rows
  const u16* BgP[4];
  u16* sBw[4];
#pragma unroll
  for (int g = 0; g < 4; g++) {
    int rt = 32 * wave + 8 * g + lrow8;
    BgP[g] = Bp + (size_t)(n0 + rt) * Bstr + kb + sch;
    sBw[g] = &sB[(32 * wave + 8 * g) * BK];
  }

  f32x4 acc[2][4] = {};

  for (int k0 = 0; k0 < KL; k0 += BK) {
#pragma unroll
    for (int g = 0; g < 2; g++) gload_lds16(AgP[g] + k0, sAw[g]);
#pragma unroll
    for (int g = 0; g < 4; g++) gload_lds16(BgP[g] + k0, sBw[g]);
    __syncthreads();
#pragma unroll
    for (int ks = 0; ks < 2; ks++) {
      int ch = ((ks * 4 + kq) ^ fsw) * 8;   // un-swizzle at read
      u16x8 af[2], bf[4];
#pragma unroll
      for (int i = 0; i < 2; i++)
        af[i] = *reinterpret_cast<const u16x8*>(&sA[(wm + 16 * i + fm) * BK + ch]);
#pragma unroll
      for (int j = 0; j < 4; j++)
        bf[j] = *reinterpret_cast<const u16x8*>(&sB[(wn + 16 * j + fm) * BK + ch]);
#pragma unroll
      for (int i = 0; i < 2; i++)
#pragma unroll
        for (int j = 0; j < 4; j++)
          acc[i][j] = mfma16(af[i], bf[j], acc[i][j]);
    }
    __syncthreads();
  }

  // epilogue: C/D mapping col = lane&15, row = (lane>>4)*4 + reg (m89/m91)
#pragma unroll
  for (int i = 0; i < 2; i++) {
#pragma unroll
    for (int j = 0; j < 4; j++) {
      int gn = n0 + wn + 16 * j + fm;
      f32x4 a = acc[i][j];
#pragma unroll
      for (int r = 0; r < 4; r++) {
        int gm = m0 + wm + 16 * i + kq * 4 + r;
        if (gm < Mloc) {
          float v = a[r];
          if (PHASE == 0) {
            float tq = fmaxf(v, 0.f);
            if (!sh) {
              tq = tq * tq * rowscale[rowbase + gm];
              HgOut[(size_t)(rowbase + gm) * IDIM + gn] = f2bf(tq);
            } else {
              HsOut[(size_t)gm * ISDIM + gn] = f2bf(tq * tq);
            }
          } else {
            if (!sh) Ygb[(size_t)(rowbase + gm) * HDIM + gn] = f2bf(v);
            else     Ys[(size_t)(half * T_TOK + gm) * HDIM + gn] = v;
          }
        }
      }
    }
  }
}

// ---- combine: out[t] = Ys0[t] + Ys1[t] + sum_k Ygb[slot_of[t,k]] ---------
__global__ void __launch_bounds__(256) combine_kernel(
    const u16* __restrict__ Ygb, const float* __restrict__ Ys,
    const int* __restrict__ slot_of, float* __restrict__ out) {
  int t = blockIdx.x;
  int i = threadIdx.x;                       // 256 x 4 elems = 1024
  int4 s = *reinterpret_cast<const int4*>(&slot_of[t * 4]);
  const ushort4* Y4 = reinterpret_cast<const ushort4*>(Ygb);
  const float4* S4 = reinterpret_cast<const float4*>(Ys);
  float4* O4 = reinterpret_cast<float4*>(out);
  float4 v0 = S4[(size_t)t * 256 + i];
  float4 v1 = S4[(size_t)(T_TOK + t) * 256 + i];
  ushort4 a = Y4[(size_t)s.x * 256 + i];
  ushort4 b = Y4[(size_t)s.y * 256 + i];
  ushort4 c = Y4[(size_t)s.z * 256 + i];
  ushort4 d = Y4[(size_t)s.w * 256 + i];
  float4 v;
  v.x = v0.x + v1.x + bf2f(a.x) + bf2f(b.x) + bf2f(c.x) + bf2f(d.x);
  v.y = v0.y + v1.y + bf2f(a.y) + bf2f(b.y) + bf2f(c.y) + bf2f(d.y);
  v.z = v0.z + v1.z + bf2f(a.z) + bf2f(b.z) + bf2f(c.z) + bf2f(d.z);
  v.w = v0.w + v1.w + bf2f(a.w) + bf2f(b.w) + bf2f(c.w) + bf2f(d.w);
  O4[(size_t)t * 256 + i] = v;
}

// ---------------- launcher ----------------
extern "C" void kernel_launch(void* const* d_in, const int* in_sizes, int n_in,
                              void* d_out, int out_size, void* d_ws, size_t ws_size,
                              hipStream_t stream) {
  const float* x    = (const float*)d_in[0];
  const float* Wg   = (const float*)d_in[1];
  const float* bias = (const float*)d_in[2];
  const float* W1   = (const float*)d_in[3];
  const float* W2   = (const float*)d_in[4];
  const float* Ws1  = (const float*)d_in[5];
  const float* Ws2  = (const float*)d_in[6];
  float* out = (float*)d_out;

  char* p = (char*)d_ws;
  auto alloc = [&](size_t bytes) -> void* {
    void* r = (void*)p;
    p += (bytes + 255) & ~(size_t)255;
    return r;
  };
  int*   topk_idx   = (int*)  alloc((size_t)NSLOT * 4);
  float* topk_w     = (float*)alloc((size_t)NSLOT * 4);
  int*   counts     = (int*)  alloc(64);
  int*   offsets    = (int*)  alloc(64);
  int*   perm_token = (int*)  alloc((size_t)NSLOT * 4);
  float* perm_w     = (float*)alloc((size_t)NSLOT * 4);
  int*   slot_of    = (int*)  alloc((size_t)NSLOT * 4);
  u16*   Xbf        = (u16*)  alloc((size_t)T_TOK * HDIM * 2);
  u16*   W1b        = (u16*)  alloc((size_t)NEXP * IDIM * HDIM * 2);
  u16*   W2b        = (u16*)  alloc((size_t)NEXP * HDIM * IDIM * 2);
  u16*   Ws1b      = (u16*)  alloc((size_t)ISDIM * HDIM * 2);
  u16*   Ws2b      = (u16*)  alloc((size_t)HDIM * ISDIM * 2);
  u16*   Hg         = (u16*)  alloc((size_t)NSLOT * IDIM * 2);
  u16*   Hs         = (u16*)  alloc((size_t)T_TOK * ISDIM * 2);
  u16*   Ygb        = (u16*)  alloc((size_t)NSLOT * HDIM * 2);
  float* Ys         = (float*)alloc((size_t)2 * T_TOK * HDIM * 4);

  router_kernel<<<T_TOK, 256, 0, stream>>>(x, Wg, bias, topk_idx, topk_w, Xbf);
  route_build<<<1, 256, 0, stream>>>(topk_idx, topk_w, offsets, counts,
                                     perm_token, perm_w, slot_of);

  // one fused weight-conversion launch (was 4 kernels)
  cvt_all<<<(2 * N1Q + 2 * NSQ + 255) / 256, 256, 0, stream>>>(
      W1, W2, Ws1, Ws2, W1b, W2b, Ws1b, Ws2b);

  // phase A: routed up (e<16, N=512) + shared up (e=16), one launch
  moe_gemm<0><<<dim3(T_TOK / BM, ISDIM / BN, NEXP + 1), 256, 0, stream>>>(
      Xbf, Hg, Hs, W1b, W2b, Ws1b, Ws2b, offsets, counts,
      perm_token, perm_w, Hg, Hs, nullptr, nullptr);

  // phase B: routed down (e<16) + shared down split-K (e=16,17), one launch
  moe_gemm<1><<<dim3(T_TOK / BM, HDIM / BN, NEXP + 2), 256, 0, stream>>>(
      Xbf, Hg, Hs, W1b, W2b, Ws1b, Ws2b, offsets, counts,
      perm_token, perm_w, Hg, Hs, Ygb, Ys);

  // combine: out[t] = Ys0 + Ys1 + sum_k Ygb[slot_of[t,k]]
  combine_kernel<<<T_TOK, 256, 0, stream>>>(Ygb, Ys, slot_of, out);
}